// Round 1
// baseline (491.638 us; speedup 1.0000x reference)
//
#include <hip/hip_runtime.h>
#include <stdint.h>

// ---------------------------------------------------------------------------
// LinearAttention (B=4, S=4096, HID=1024, H=16, D=64), chunked formulation.
//   Q = phi(x Wq + bq), K = phi(x Wk + bk), V = x Wv + bv   (phi = elu+1)
//   per chunk c (C=64 rows): KVT_c = V_c^T K_c (stored [e][d]), Ks_c = sum K_c
//   exclusive prefix over chunks -> KVpreT (bf16), Kspre (f32)
//   out_c = (Q_c KVpre + tril(Q_c K_c^T) V_c) / (Q_c Kspre + rowsum + eps)
//   final = attn @ Wo + bo
// All big GEMMs use v_mfma_f32_16x16x32_bf16 (A: row=l&15, k=(l>>4)*8+j;
// B: col=l&15, k=(l>>4)*8+j; C/D: col=lane&15, row=(lane>>4)*4+reg).
// ---------------------------------------------------------------------------

#define DEVI __device__ __forceinline__

typedef __attribute__((ext_vector_type(8))) short bf16x8;
typedef __attribute__((ext_vector_type(4))) float f32x4;
typedef unsigned short u16;

DEVI u16 f2bf(float f) {
  union { float f; uint32_t u; } x; x.f = f;
  return (u16)((x.u + 0x7FFFu + ((x.u >> 16) & 1u)) >> 16);  // RNE
}
DEVI float bf2f(u16 u) {
  union { uint32_t u; float f; } x; x.u = ((uint32_t)u) << 16;
  return x.f;
}
DEVI f32x4 mfma16(bf16x8 a, bf16x8 b, f32x4 c) {
  return __builtin_amdgcn_mfma_f32_16x16x32_bf16(a, b, c, 0, 0, 0);
}

static constexpr int Ss  = 4096;
static constexpr int Hh  = 16;
static constexpr int CC  = 64;          // chunk length
static constexpr int NCC = Ss / CC;     // 64 chunks

// ---------------------------------------------------------------------------
// K0: weight transpose + fp32->bf16:  out[n][k] = bf16(in[k][n]),  1024x1024
// ---------------------------------------------------------------------------
__global__ __launch_bounds__(256) void transpose_cvt_k(const float* __restrict__ in,
                                                       u16* __restrict__ out) {
  __shared__ float tl[32][33];
  const int tx = threadIdx.x & 31, ty = threadIdx.x >> 5;
  const int bx = blockIdx.x, by = blockIdx.y;
#pragma unroll
  for (int j = 0; j < 4; ++j)
    tl[ty + j * 8][tx] = in[(size_t)(by * 32 + ty + j * 8) * 1024 + bx * 32 + tx];
  __syncthreads();
#pragma unroll
  for (int j = 0; j < 4; ++j)
    out[(size_t)(bx * 32 + ty + j * 8) * 1024 + by * 32 + tx] = f2bf(tl[tx][ty + j * 8]);
}

// ---------------------------------------------------------------------------
// K1/K5: C = act(A @ B + bias); A [M,K] fp32 or bf16 row-major,
// B passed pre-transposed bf16 BT[N][K]; 128x128 tile, BK=32, double-buffered.
// ACT: 0 = none, 1 = elu+1. OUTF32: store fp32 else bf16.
// ---------------------------------------------------------------------------
template <int ACT, bool ABF16, bool OUTF32>
__global__ __launch_bounds__(256) void gemm_bt_k(const void* __restrict__ Ap,
                                                 const u16* __restrict__ BT,
                                                 const float* __restrict__ bias,
                                                 void* __restrict__ Cp,
                                                 int M, int N, int K) {
  __shared__ u16 As[2][128][40];  // +8 pad: 80B row stride -> conflict-light b128 reads
  __shared__ u16 Bs[2][128][40];
  const int t = threadIdx.x;
  const int lane = t & 63, w = t >> 6;
  const int wm = w >> 1, wn = w & 1;
  const int m0 = blockIdx.y * 128, n0 = blockIdx.x * 128;
  const int r = t >> 1, cseg = (t & 1) * 16;

  f32x4 acc[4][4];
#pragma unroll
  for (int i = 0; i < 4; ++i)
#pragma unroll
    for (int j = 0; j < 4; ++j) acc[i][j] = f32x4{0.f, 0.f, 0.f, 0.f};

  auto stage = [&](int sb, int kt) {
    const int k0 = kt * 32 + cseg;
    if constexpr (ABF16) {
      const u16* ap = (const u16*)Ap + (size_t)(m0 + r) * K + k0;
      *(uint4*)&As[sb][r][cseg]     = ((const uint4*)ap)[0];
      *(uint4*)&As[sb][r][cseg + 8] = ((const uint4*)ap)[1];
    } else {
      const float* ap = (const float*)Ap + (size_t)(m0 + r) * K + k0;
      const float4 f0 = ((const float4*)ap)[0];
      const float4 f1 = ((const float4*)ap)[1];
      const float4 f2 = ((const float4*)ap)[2];
      const float4 f3 = ((const float4*)ap)[3];
      union { uint4 v; u16 s[8]; } u0, u1;
      u0.s[0] = f2bf(f0.x); u0.s[1] = f2bf(f0.y); u0.s[2] = f2bf(f0.z); u0.s[3] = f2bf(f0.w);
      u0.s[4] = f2bf(f1.x); u0.s[5] = f2bf(f1.y); u0.s[6] = f2bf(f1.z); u0.s[7] = f2bf(f1.w);
      u1.s[0] = f2bf(f2.x); u1.s[1] = f2bf(f2.y); u1.s[2] = f2bf(f2.z); u1.s[3] = f2bf(f2.w);
      u1.s[4] = f2bf(f3.x); u1.s[5] = f2bf(f3.y); u1.s[6] = f2bf(f3.z); u1.s[7] = f2bf(f3.w);
      *(uint4*)&As[sb][r][cseg]     = u0.v;
      *(uint4*)&As[sb][r][cseg + 8] = u1.v;
    }
    const u16* bp = BT + (size_t)(n0 + r) * K + k0;
    *(uint4*)&Bs[sb][r][cseg]     = ((const uint4*)bp)[0];
    *(uint4*)&Bs[sb][r][cseg + 8] = ((const uint4*)bp)[1];
  };

  stage(0, 0);
  __syncthreads();
  const int nk = K >> 5;
  int buf = 0;
  for (int kt = 0; kt < nk; ++kt) {
    if (kt + 1 < nk) stage(buf ^ 1, kt + 1);
    bf16x8 af[4], bfr[4];
#pragma unroll
    for (int fi = 0; fi < 4; ++fi)
      af[fi] = *(const bf16x8*)&As[buf][wm * 64 + fi * 16 + (lane & 15)][(lane >> 4) * 8];
#pragma unroll
    for (int fj = 0; fj < 4; ++fj)
      bfr[fj] = *(const bf16x8*)&Bs[buf][wn * 64 + fj * 16 + (lane & 15)][(lane >> 4) * 8];
#pragma unroll
    for (int fi = 0; fi < 4; ++fi)
#pragma unroll
      for (int fj = 0; fj < 4; ++fj)
        acc[fi][fj] = mfma16(af[fi], bfr[fj], acc[fi][fj]);
    __syncthreads();
    buf ^= 1;
  }

#pragma unroll
  for (int fj = 0; fj < 4; ++fj) {
    const int col = n0 + wn * 64 + fj * 16 + (lane & 15);
    const float bv = bias[col];
#pragma unroll
    for (int fi = 0; fi < 4; ++fi) {
#pragma unroll
      for (int rr = 0; rr < 4; ++rr) {
        const int row = m0 + wm * 64 + fi * 16 + (lane >> 4) * 4 + rr;
        float v = acc[fi][fj][rr] + bv;
        if (ACT == 1) v = (v > 0.f) ? (v + 1.f) : __expf(v);
        if constexpr (OUTF32)
          ((float*)Cp)[(size_t)row * N + col] = v;
        else
          ((u16*)Cp)[(size_t)row * N + col] = f2bf(v);
      }
    }
  }
}

// ---------------------------------------------------------------------------
// K2: per-chunk KVT_c[e][d] = sum_i V[i][e]*K[i][d]  (bf16 out), Ks_c[d] (f32)
// grid (NCC, H, B), 256 threads
// ---------------------------------------------------------------------------
__global__ __launch_bounds__(256) void chunk_kv_k(const u16* __restrict__ Kb,
                                                  const u16* __restrict__ Vb,
                                                  u16* __restrict__ KVTc,
                                                  float* __restrict__ Ksc) {
  const int c = blockIdx.x, h = blockIdx.y, b = blockIdx.z;
  __shared__ u16 Kl[64][72], Vl[64][72];
  const int t = threadIdx.x;
  {
    const int i = t >> 2, c0 = (t & 3) * 16;
    const size_t g = ((size_t)(b * Ss + c * CC + i)) * 1024 + h * 64 + c0;
    const uint4* kp = (const uint4*)(Kb + g);
    uint4* kd = (uint4*)&Kl[i][c0]; kd[0] = kp[0]; kd[1] = kp[1];
    const uint4* vp = (const uint4*)(Vb + g);
    uint4* vd = (uint4*)&Vl[i][c0]; vd[0] = vp[0]; vd[1] = vp[1];
  }
  __syncthreads();
  const int e = t >> 2, d0 = (t & 3) * 16;
  float acc[16];
#pragma unroll
  for (int j = 0; j < 16; ++j) acc[j] = 0.f;
  for (int i = 0; i < 64; ++i) {
    const float v = bf2f(Vl[i][e]);
    const bf16x8 k0 = *(const bf16x8*)&Kl[i][d0];
    const bf16x8 k1 = *(const bf16x8*)&Kl[i][d0 + 8];
#pragma unroll
    for (int j = 0; j < 8; ++j) acc[j]     += v * bf2f((u16)k0[j]);
#pragma unroll
    for (int j = 0; j < 8; ++j) acc[j + 8] += v * bf2f((u16)k1[j]);
  }
  const size_t base = ((size_t)((b * Hh + h) * NCC + c)) * 4096 + (size_t)e * 64 + d0;
#pragma unroll
  for (int j = 0; j < 16; ++j) KVTc[base + j] = f2bf(acc[j]);
  if (t < 64) {
    float s = 0.f;
    for (int i = 0; i < 64; ++i) s += bf2f(Kl[i][t]);
    Ksc[((size_t)((b * Hh + h) * NCC + c)) * 64 + t] = s;
  }
}

// ---------------------------------------------------------------------------
// K3: exclusive prefix over chunks per (b,h).  grid 64, 256 threads.
// KVpreT bf16 (f32 running accum), Kspre f32.
// ---------------------------------------------------------------------------
__global__ __launch_bounds__(256) void prefix_k(const u16* __restrict__ KVTc,
                                                const float* __restrict__ Ksc,
                                                u16* __restrict__ KVpreT,
                                                float* __restrict__ Kspre) {
  const int bh = blockIdx.x;
  const int t = threadIdx.x;
  float run[16];
#pragma unroll
  for (int j = 0; j < 16; ++j) run[j] = 0.f;
  float rk = 0.f;
  for (int c = 0; c < NCC; ++c) {
    const size_t base = ((size_t)(bh * NCC + c)) * 4096;
#pragma unroll
    for (int j = 0; j < 16; ++j) {
      const size_t idx = base + (size_t)j * 256 + t;
      KVpreT[idx] = f2bf(run[j]);
      run[j] += bf2f(KVTc[idx]);
    }
    if (t < 64) {
      const size_t kb = ((size_t)(bh * NCC + c)) * 64 + t;
      Kspre[kb] = rk;
      rk += Ksc[kb];
    }
  }
}

// ---------------------------------------------------------------------------
// K4: per-(b,h,c) chunk output.  grid (NCC, H, B), 256 threads (4 waves).
// Wave w owns rows [w*16, w*16+16).
// ---------------------------------------------------------------------------
__global__ __launch_bounds__(256) void chunk_out_k(const u16* __restrict__ Qb,
                                                   const u16* __restrict__ Kb,
                                                   const u16* __restrict__ Vb,
                                                   const u16* __restrict__ KVpreT,
                                                   const float* __restrict__ Kspre,
                                                   u16* __restrict__ attn) {
  const int c = blockIdx.x, h = blockIdx.y, b = blockIdx.z;
  const int bh = b * Hh + h;
  __shared__ u16 Ql[64][72], Kl[64][72], VT[64][72], Pl[64][72];
  __shared__ float den[64];
  const int t = threadIdx.x, lane = t & 63, w = t >> 6;

  {
    const int i = t >> 2, c0 = (t & 3) * 16;
    const size_t g = ((size_t)(b * Ss + c * CC + i)) * 1024 + h * 64 + c0;
    const uint4* qp = (const uint4*)(Qb + g);
    uint4* qd = (uint4*)&Ql[i][c0]; qd[0] = qp[0]; qd[1] = qp[1];
    const uint4* kp = (const uint4*)(Kb + g);
    uint4* kd = (uint4*)&Kl[i][c0]; kd[0] = kp[0]; kd[1] = kp[1];
    const u16* vp = Vb + g;
#pragma unroll
    for (int j = 0; j < 16; ++j) VT[c0 + j][i] = vp[j];  // transpose V -> [e][i]
  }
  __syncthreads();

  // Phase A: S = Q K^T for rows w*16..+15, all 64 cols
  f32x4 sacc[4];
#pragma unroll
  for (int fj = 0; fj < 4; ++fj) sacc[fj] = f32x4{0.f, 0.f, 0.f, 0.f};
#pragma unroll
  for (int kd = 0; kd < 2; ++kd) {
    const bf16x8 aq = *(const bf16x8*)&Ql[w * 16 + (lane & 15)][kd * 32 + (lane >> 4) * 8];
#pragma unroll
    for (int fj = 0; fj < 4; ++fj) {
      const bf16x8 bk = *(const bf16x8*)&Kl[fj * 16 + (lane & 15)][kd * 32 + (lane >> 4) * 8];
      sacc[fj] = mfma16(aq, bk, sacc[fj]);
    }
  }
  // mask (j<=i), write P (bf16), accumulate row sums
  float rowsum[4] = {0.f, 0.f, 0.f, 0.f};
#pragma unroll
  for (int fj = 0; fj < 4; ++fj) {
#pragma unroll
    for (int rr = 0; rr < 4; ++rr) {
      const int i_loc = w * 16 + (lane >> 4) * 4 + rr;
      const int j_loc = fj * 16 + (lane & 15);
      const float v = (j_loc <= i_loc) ? sacc[fj][rr] : 0.f;
      Pl[i_loc][j_loc] = f2bf(v);
      rowsum[rr] += v;
    }
  }
#pragma unroll
  for (int off = 1; off < 16; off <<= 1) {
#pragma unroll
    for (int rr = 0; rr < 4; ++rr) rowsum[rr] += __shfl_xor(rowsum[rr], off, 64);
  }
  if ((lane & 15) == 0) {
#pragma unroll
    for (int rr = 0; rr < 4; ++rr) den[w * 16 + (lane >> 4) * 4 + rr] = rowsum[rr];
  }
  __syncthreads();
  if (t < 64) {
    const float* ks = Kspre + ((size_t)(bh * NCC + c)) * 64;
    float s = den[t] + 1e-6f;
    for (int d2 = 0; d2 < 64; ++d2) s += bf2f(Ql[t][d2]) * ks[d2];
    den[t] = s;
  }
  __syncthreads();

  // Phase B: O = Q @ KVpre + P @ V
  f32x4 oacc[4];
#pragma unroll
  for (int fj = 0; fj < 4; ++fj) oacc[fj] = f32x4{0.f, 0.f, 0.f, 0.f};
  const u16* kvb = KVpreT + ((size_t)(bh * NCC + c)) * 4096;
#pragma unroll
  for (int ks2 = 0; ks2 < 2; ++ks2) {
    const bf16x8 aq = *(const bf16x8*)&Ql[w * 16 + (lane & 15)][ks2 * 32 + (lane >> 4) * 8];
#pragma unroll
    for (int fj = 0; fj < 4; ++fj) {
      const bf16x8 bv =
          *(const bf16x8*)(kvb + (size_t)(fj * 16 + (lane & 15)) * 64 + ks2 * 32 + (lane >> 4) * 8);
      oacc[fj] = mfma16(aq, bv, oacc[fj]);
    }
  }
#pragma unroll
  for (int ks3 = 0; ks3 < 2; ++ks3) {
    const bf16x8 ap = *(const bf16x8*)&Pl[w * 16 + (lane & 15)][ks3 * 32 + (lane >> 4) * 8];
#pragma unroll
    for (int fj = 0; fj < 4; ++fj) {
      const bf16x8 bv = *(const bf16x8*)&VT[fj * 16 + (lane & 15)][ks3 * 32 + (lane >> 4) * 8];
      oacc[fj] = mfma16(ap, bv, oacc[fj]);
    }
  }
#pragma unroll
  for (int fj = 0; fj < 4; ++fj) {
#pragma unroll
    for (int rr = 0; rr < 4; ++rr) {
      const int i_loc = w * 16 + (lane >> 4) * 4 + rr;
      const int e = fj * 16 + (lane & 15);
      const float v = oacc[fj][rr] / den[i_loc];
      attn[((size_t)(b * Ss + c * CC + i_loc)) * 1024 + h * 64 + e] = f2bf(v);
    }
  }
}

// ---------------------------------------------------------------------------
extern "C" void kernel_launch(void* const* d_in, const int* in_sizes, int n_in,
                              void* d_out, int out_size, void* d_ws, size_t ws_size,
                              hipStream_t stream) {
  (void)in_sizes; (void)n_in; (void)out_size; (void)ws_size;
  const float* x  = (const float*)d_in[0];
  const float* Wq = (const float*)d_in[1];
  const float* bq = (const float*)d_in[2];
  const float* Wk = (const float*)d_in[3];
  const float* bk = (const float*)d_in[4];
  const float* Wv = (const float*)d_in[5];
  const float* bv = (const float*)d_in[6];
  const float* Wo = (const float*)d_in[7];
  const float* bo = (const float*)d_in[8];
  float* out = (float*)d_out;
  char* ws = (char*)d_ws;

  size_t off = 0;
  auto take = [&](size_t bytes) { size_t r = off; off += (bytes + 255) & ~(size_t)255; return r; };
  const size_t WT_B   = (size_t)1024 * 1024 * 2;        // 2 MB each
  const size_t BIG_B  = (size_t)16384 * 1024 * 2;       // 32 MB each (bf16 [M][1024])
  const size_t KVT_B  = (size_t)64 * NCC * 4096 * 2;    // 32 MB bf16
  const size_t KS_B   = (size_t)64 * NCC * 64 * 4;      // 1 MB f32

  u16* WqT    = (u16*)(ws + take(WT_B));
  u16* WkT    = (u16*)(ws + take(WT_B));
  u16* WvT    = (u16*)(ws + take(WT_B));
  u16* WoT    = (u16*)(ws + take(WT_B));
  u16* Qb     = (u16*)(ws + take(BIG_B));
  u16* Kb     = (u16*)(ws + take(BIG_B));
  u16* Vb     = (u16*)(ws + take(BIG_B));
  size_t kvtc_off = take(KVT_B);
  u16* KVTc   = (u16*)(ws + kvtc_off);
  u16* attn   = (u16*)(ws + kvtc_off);                  // alias: KVTc dead after prefix_k
  u16* KVpreT = (u16*)(ws + take(KVT_B));
  float* Ksc  = (float*)(ws + take(KS_B));
  float* Kspre= (float*)(ws + take(KS_B));

  const dim3 blk(256);
  const dim3 gT(32, 32);
  transpose_cvt_k<<<gT, blk, 0, stream>>>(Wq, WqT);
  transpose_cvt_k<<<gT, blk, 0, stream>>>(Wk, WkT);
  transpose_cvt_k<<<gT, blk, 0, stream>>>(Wv, WvT);
  transpose_cvt_k<<<gT, blk, 0, stream>>>(Wo, WoT);

  const dim3 gG(8, 128);  // N/128, M/128
  gemm_bt_k<1, false, false><<<gG, blk, 0, stream>>>(x, WqT, bq, Qb, 16384, 1024, 1024);
  gemm_bt_k<1, false, false><<<gG, blk, 0, stream>>>(x, WkT, bk, Kb, 16384, 1024, 1024);
  gemm_bt_k<0, false, false><<<gG, blk, 0, stream>>>(x, WvT, bv, Vb, 16384, 1024, 1024);

  const dim3 gC(NCC, Hh, 4);
  chunk_kv_k<<<gC, blk, 0, stream>>>(Kb, Vb, KVTc, Ksc);
  prefix_k<<<dim3(64), blk, 0, stream>>>(KVTc, Ksc, KVpreT, Kspre);
  chunk_out_k<<<gC, blk, 0, stream>>>(Qb, Kb, Vb, KVpreT, Kspre, attn);

  gemm_bt_k<0, true, true><<<gG, blk, 0, stream>>>(attn, WoT, bo, out, 16384, 1024, 1024);
}

// Round 2
// 352.048 us; speedup vs baseline: 1.3965x; 1.3965x over previous
//
#include <hip/hip_runtime.h>
#include <stdint.h>

// ---------------------------------------------------------------------------
// LinearAttention (B=4, S=4096, HID=1024, H=16, D=64), chunked formulation.
// Round 2: x->bf16 once; fused QKV GEMM (N=3072) + Wo GEMM both in the m97
// structure (global_load_lds width-16, linear 128x32 LDS tiles, 2-barrier
// K-loop); prefix kernel parallelized 4x.
// ---------------------------------------------------------------------------

#define DEVI __device__ __forceinline__

typedef __attribute__((ext_vector_type(8))) short bf16x8;
typedef __attribute__((ext_vector_type(4))) float f32x4;
typedef unsigned short u16;

DEVI u16 f2bf(float f) {
  union { float f; uint32_t u; } x; x.f = f;
  return (u16)((x.u + 0x7FFFu + ((x.u >> 16) & 1u)) >> 16);  // RNE
}
DEVI float bf2f(u16 u) {
  union { uint32_t u; float f; } x; x.u = ((uint32_t)u) << 16;
  return x.f;
}
DEVI f32x4 mfma16(bf16x8 a, bf16x8 b, f32x4 c) {
  return __builtin_amdgcn_mfma_f32_16x16x32_bf16(a, b, c, 0, 0, 0);
}

typedef __attribute__((address_space(3))) void* lds_vp;
typedef const __attribute__((address_space(1))) void* glb_vp;
DEVI void gload_lds16(const void* g, void* l) {
  __builtin_amdgcn_global_load_lds((glb_vp)g, (lds_vp)l, 16, 0, 0);
}

static constexpr int Ss  = 4096;
static constexpr int Hh  = 16;
static constexpr int CC  = 64;          // chunk length
static constexpr int NCC = Ss / CC;     // 64 chunks

// ---------------------------------------------------------------------------
// x (fp32) -> bf16, 8 elems/thread
// ---------------------------------------------------------------------------
__global__ __launch_bounds__(256) void cvt_bf16_k(const float* __restrict__ in,
                                                  u16* __restrict__ out, int n8) {
  const int i = blockIdx.x * 256 + threadIdx.x;
  if (i >= n8) return;
  const float4* p = (const float4*)(in + (size_t)i * 8);
  const float4 a = p[0], b = p[1];
  union { uint4 v; u16 s[8]; } u;
  u.s[0] = f2bf(a.x); u.s[1] = f2bf(a.y); u.s[2] = f2bf(a.z); u.s[3] = f2bf(a.w);
  u.s[4] = f2bf(b.x); u.s[5] = f2bf(b.y); u.s[6] = f2bf(b.z); u.s[7] = f2bf(b.w);
  ((uint4*)out)[i] = u.v;
}

// ---------------------------------------------------------------------------
// weight transpose + fp32->bf16:  out[n][k] = bf16(in[k][n]),  1024x1024
// ---------------------------------------------------------------------------
__global__ __launch_bounds__(256) void transpose_cvt_k(const float* __restrict__ in,
                                                       u16* __restrict__ out) {
  __shared__ float tl[32][33];
  const int tx = threadIdx.x & 31, ty = threadIdx.x >> 5;
  const int bx = blockIdx.x, by = blockIdx.y;
#pragma unroll
  for (int j = 0; j < 4; ++j)
    tl[ty + j * 8][tx] = in[(size_t)(by * 32 + ty + j * 8) * 1024 + bx * 32 + tx];
  __syncthreads();
#pragma unroll
  for (int j = 0; j < 4; ++j)
    out[(size_t)(bx * 32 + ty + j * 8) * 1024 + by * 32 + tx] = f2bf(tl[tx][ty + j * 8]);
}

// ---------------------------------------------------------------------------
// m97-structure GEMM: C = act(A @ BT^T + bias), A bf16 [M][K], BT bf16 [N][K].
// 128x128 tile, BK=32, global_load_lds w16, linear LDS, 2-barrier K-loop.
// FUSED: N=3072, segments {Q(elu+1,b0), K(elu+1,b1), V(none,b2)} each 1024
//        wide, bf16 out at out + seg*M*1024.
// else:  N=1024, bias b0, fp32 out (final projection).
// ---------------------------------------------------------------------------
template <bool FUSED, bool OUTF32>
__global__ __launch_bounds__(256) void gemm97_k(const u16* __restrict__ A,
                                                const u16* __restrict__ BT,
                                                const float* __restrict__ b0,
                                                const float* __restrict__ b1,
                                                const float* __restrict__ b2,
                                                void* __restrict__ out,
                                                int M, int K) {
  __shared__ __attribute__((aligned(16))) u16 As[128 * 32];
  __shared__ __attribute__((aligned(16))) u16 Bs[128 * 32];
  const int t = threadIdx.x, lane = t & 63, w = t >> 6;
  const int wm = w >> 1, wn = w & 1;
  const int m0 = blockIdx.y * 128, n0 = blockIdx.x * 128;

  // staging geometry: 2 calls per thread per matrix; region idx = w*2+j covers
  // LDS rows [idx*16, idx*16+16), lane -> row idx*16 + lane/4, col (lane&3)*8
  const int srow0 = (w * 2 + 0) * 16 + (lane >> 2);
  const int srow1 = (w * 2 + 1) * 16 + (lane >> 2);
  const int kseg  = (lane & 3) * 8;
  const u16* gA0 = A + (size_t)(m0 + srow0) * K + kseg;
  const u16* gA1 = A + (size_t)(m0 + srow1) * K + kseg;
  const u16* gB0 = BT + (size_t)(n0 + srow0) * K + kseg;
  const u16* gB1 = BT + (size_t)(n0 + srow1) * K + kseg;
  u16* lA0 = As + (w * 2 + 0) * 512 + lane * 8;
  u16* lA1 = As + (w * 2 + 1) * 512 + lane * 8;
  u16* lB0 = Bs + (w * 2 + 0) * 512 + lane * 8;
  u16* lB1 = Bs + (w * 2 + 1) * 512 + lane * 8;

  f32x4 acc[4][4];
#pragma unroll
  for (int i = 0; i < 4; ++i)
#pragma unroll
    for (int j = 0; j < 4; ++j) acc[i][j] = f32x4{0.f, 0.f, 0.f, 0.f};

  const int fr = lane & 15, ks = (lane >> 4) * 8;
  const int nk = K >> 5;
  for (int kt = 0; kt < nk; ++kt) {
    const int ko = kt * 32;
    gload_lds16(gA0 + ko, lA0);
    gload_lds16(gA1 + ko, lA1);
    gload_lds16(gB0 + ko, lB0);
    gload_lds16(gB1 + ko, lB1);
    __syncthreads();  // drains vmcnt -> LDS tile ready
    bf16x8 af[4], bg[4];
#pragma unroll
    for (int fi = 0; fi < 4; ++fi)
      af[fi] = *(const bf16x8*)&As[(wm * 64 + fi * 16 + fr) * 32 + ks];
#pragma unroll
    for (int fj = 0; fj < 4; ++fj)
      bg[fj] = *(const bf16x8*)&Bs[(wn * 64 + fj * 16 + fr) * 32 + ks];
#pragma unroll
    for (int fi = 0; fi < 4; ++fi)
#pragma unroll
      for (int fj = 0; fj < 4; ++fj)
        acc[fi][fj] = mfma16(af[fi], bg[fj], acc[fi][fj]);
    __syncthreads();
  }

#pragma unroll
  for (int fj = 0; fj < 4; ++fj) {
    const int ncol = n0 + wn * 64 + fj * 16 + (lane & 15);
    int seg = 0, lcol = ncol;
    const float* bp = b0;
    if constexpr (FUSED) {
      seg = ncol >> 10;
      lcol = ncol & 1023;
      bp = (seg == 0) ? b0 : (seg == 1) ? b1 : b2;
    }
    const float bv = bp[lcol];
#pragma unroll
    for (int fi = 0; fi < 4; ++fi) {
#pragma unroll
      for (int rr = 0; rr < 4; ++rr) {
        const int row = m0 + wm * 64 + fi * 16 + (lane >> 4) * 4 + rr;
        float v = acc[fi][fj][rr] + bv;
        if (FUSED && seg < 2) v = (v > 0.f) ? (v + 1.f) : __expf(v);
        if constexpr (OUTF32)
          ((float*)out)[(size_t)row * 1024 + ncol] = v;
        else
          ((u16*)out)[(size_t)seg * M * 1024 + (size_t)row * 1024 + lcol] = f2bf(v);
      }
    }
  }
}

// ---------------------------------------------------------------------------
// per-chunk KVT_c[e][d] = sum_i V[i][e]*K[i][d]  (bf16 out), Ks_c[d] (f32)
// grid (NCC, H, B), 256 threads
// ---------------------------------------------------------------------------
__global__ __launch_bounds__(256) void chunk_kv_k(const u16* __restrict__ Kb,
                                                  const u16* __restrict__ Vb,
                                                  u16* __restrict__ KVTc,
                                                  float* __restrict__ Ksc) {
  const int c = blockIdx.x, h = blockIdx.y, b = blockIdx.z;
  __shared__ u16 Kl[64][72], Vl[64][72];
  const int t = threadIdx.x;
  {
    const int i = t >> 2, c0 = (t & 3) * 16;
    const size_t g = ((size_t)(b * Ss + c * CC + i)) * 1024 + h * 64 + c0;
    const uint4* kp = (const uint4*)(Kb + g);
    uint4* kd = (uint4*)&Kl[i][c0]; kd[0] = kp[0]; kd[1] = kp[1];
    const uint4* vp = (const uint4*)(Vb + g);
    uint4* vd = (uint4*)&Vl[i][c0]; vd[0] = vp[0]; vd[1] = vp[1];
  }
  __syncthreads();
  const int e = t >> 2, d0 = (t & 3) * 16;
  float acc[16];
#pragma unroll
  for (int j = 0; j < 16; ++j) acc[j] = 0.f;
  for (int i = 0; i < 64; ++i) {
    const float v = bf2f(Vl[i][e]);
    const bf16x8 k0 = *(const bf16x8*)&Kl[i][d0];
    const bf16x8 k1 = *(const bf16x8*)&Kl[i][d0 + 8];
#pragma unroll
    for (int j = 0; j < 8; ++j) acc[j]     += v * bf2f((u16)k0[j]);
#pragma unroll
    for (int j = 0; j < 8; ++j) acc[j + 8] += v * bf2f((u16)k1[j]);
  }
  const size_t base = ((size_t)((b * Hh + h) * NCC + c)) * 4096 + (size_t)e * 64 + d0;
#pragma unroll
  for (int j = 0; j < 16; ++j) KVTc[base + j] = f2bf(acc[j]);
  if (t < 64) {
    float s = 0.f;
    for (int i = 0; i < 64; ++i) s += bf2f(Kl[i][t]);
    Ksc[((size_t)((b * Hh + h) * NCC + c)) * 64 + t] = s;
  }
}

// ---------------------------------------------------------------------------
// exclusive prefix over chunks per (b,h).  grid (64, 4): y splits e-rows.
// ---------------------------------------------------------------------------
__global__ __launch_bounds__(256) void prefix_k(const u16* __restrict__ KVTc,
                                                const float* __restrict__ Ksc,
                                                u16* __restrict__ KVpreT,
                                                float* __restrict__ Kspre) {
  const int bh = blockIdx.x, eg = blockIdx.y;
  const int t = threadIdx.x;
  float run[4];
#pragma unroll
  for (int j = 0; j < 4; ++j) run[j] = 0.f;
  float rk = 0.f;
  for (int c = 0; c < NCC; ++c) {
    const size_t base = ((size_t)(bh * NCC + c)) * 4096 + (size_t)eg * 1024;
#pragma unroll
    for (int j = 0; j < 4; ++j) {
      const size_t idx = base + (size_t)j * 256 + t;
      KVpreT[idx] = f2bf(run[j]);
      run[j] += bf2f(KVTc[idx]);
    }
    if (eg == 3 && t < 64) {
      const size_t kb = ((size_t)(bh * NCC + c)) * 64 + t;
      Kspre[kb] = rk;
      rk += Ksc[kb];
    }
  }
}

// ---------------------------------------------------------------------------
// per-(b,h,c) chunk output.  grid (NCC, H, B), 256 threads (4 waves).
// ---------------------------------------------------------------------------
__global__ __launch_bounds__(256) void chunk_out_k(const u16* __restrict__ Qb,
                                                   const u16* __restrict__ Kb,
                                                   const u16* __restrict__ Vb,
                                                   const u16* __restrict__ KVpreT,
                                                   const float* __restrict__ Kspre,
                                                   u16* __restrict__ attn) {
  const int c = blockIdx.x, h = blockIdx.y, b = blockIdx.z;
  const int bh = b * Hh + h;
  __shared__ u16 Ql[64][72], Kl[64][72], VT[64][72], Pl[64][72];
  __shared__ float den[64];
  const int t = threadIdx.x, lane = t & 63, w = t >> 6;

  {
    const int i = t >> 2, c0 = (t & 3) * 16;
    const size_t g = ((size_t)(b * Ss + c * CC + i)) * 1024 + h * 64 + c0;
    const uint4* qp = (const uint4*)(Qb + g);
    uint4* qd = (uint4*)&Ql[i][c0]; qd[0] = qp[0]; qd[1] = qp[1];
    const uint4* kp = (const uint4*)(Kb + g);
    uint4* kd = (uint4*)&Kl[i][c0]; kd[0] = kp[0]; kd[1] = kp[1];
    const u16* vp = Vb + g;
#pragma unroll
    for (int j = 0; j < 16; ++j) VT[c0 + j][i] = vp[j];  // transpose V -> [e][i]
  }
  __syncthreads();

  // Phase A: S = Q K^T for rows w*16..+15, all 64 cols
  f32x4 sacc[4];
#pragma unroll
  for (int fj = 0; fj < 4; ++fj) sacc[fj] = f32x4{0.f, 0.f, 0.f, 0.f};
#pragma unroll
  for (int kd = 0; kd < 2; ++kd) {
    const bf16x8 aq = *(const bf16x8*)&Ql[w * 16 + (lane & 15)][kd * 32 + (lane >> 4) * 8];
#pragma unroll
    for (int fj = 0; fj < 4; ++fj) {
      const bf16x8 bk = *(const bf16x8*)&Kl[fj * 16 + (lane & 15)][kd * 32 + (lane >> 4) * 8];
      sacc[fj] = mfma16(aq, bk, sacc[fj]);
    }
  }
  float rowsum[4] = {0.f, 0.f, 0.f, 0.f};
#pragma unroll
  for (int fj = 0; fj < 4; ++fj) {
#pragma unroll
    for (int rr = 0; rr < 4; ++rr) {
      const int i_loc = w * 16 + (lane >> 4) * 4 + rr;
      const int j_loc = fj * 16 + (lane & 15);
      const float v = (j_loc <= i_loc) ? sacc[fj][rr] : 0.f;
      Pl[i_loc][j_loc] = f2bf(v);
      rowsum[rr] += v;
    }
  }
#pragma unroll
  for (int off = 1; off < 16; off <<= 1) {
#pragma unroll
    for (int rr = 0; rr < 4; ++rr) rowsum[rr] += __shfl_xor(rowsum[rr], off, 64);
  }
  if ((lane & 15) == 0) {
#pragma unroll
    for (int rr = 0; rr < 4; ++rr) den[w * 16 + (lane >> 4) * 4 + rr] = rowsum[rr];
  }
  __syncthreads();
  if (t < 64) {
    const float* ksp = Kspre + ((size_t)(bh * NCC + c)) * 64;
    float s = den[t] + 1e-6f;
    for (int d2 = 0; d2 < 64; ++d2) s += bf2f(Ql[t][d2]) * ksp[d2];
    den[t] = s;
  }
  __syncthreads();

  // Phase B: O = Q @ KVpre + P @ V
  f32x4 oacc[4];
#pragma unroll
  for (int fj = 0; fj < 4; ++fj) oacc[fj] = f32x4{0.f, 0.f, 0.f, 0.f};
  const u16* kvb = KVpreT + ((size_t)(bh * NCC + c)) * 4096;
#pragma unroll
  for (int ks2 = 0; ks2 < 2; ++ks2) {
    const bf16x8 aq = *(const bf16x8*)&Ql[w * 16 + (lane & 15)][ks2 * 32 + (lane >> 4) * 8];
#pragma unroll
    for (int fj = 0; fj < 4; ++fj) {
      const bf16x8 bv =
          *(const bf16x8*)(kvb + (size_t)(fj * 16 + (lane & 15)) * 64 + ks2 * 32 + (lane >> 4) * 8);
      oacc[fj] = mfma16(aq, bv, oacc[fj]);
    }
  }
#pragma unroll
  for (int ks3 = 0; ks3 < 2; ++ks3) {
    const bf16x8 ap = *(const bf16x8*)&Pl[w * 16 + (lane & 15)][ks3 * 32 + (lane >> 4) * 8];
#pragma unroll
    for (int fj = 0; fj < 4; ++fj) {
      const bf16x8 bv = *(const bf16x8*)&VT[fj * 16 + (lane & 15)][ks3 * 32 + (lane >> 4) * 8];
      oacc[fj] = mfma16(ap, bv, oacc[fj]);
    }
  }
#pragma unroll
  for (int fj = 0; fj < 4; ++fj) {
#pragma unroll
    for (int rr = 0; rr < 4; ++rr) {
      const int i_loc = w * 16 + (lane >> 4) * 4 + rr;
      const int e = fj * 16 + (lane & 15);
      const float v = oacc[fj][rr] / den[i_loc];
      attn[((size_t)(b * Ss + c * CC + i_loc)) * 1024 + h * 64 + e] = f2bf(v);
    }
  }
}

// ---------------------------------------------------------------------------
extern "C" void kernel_launch(void* const* d_in, const int* in_sizes, int n_in,
                              void* d_out, int out_size, void* d_ws, size_t ws_size,
                              hipStream_t stream) {
  (void)in_sizes; (void)n_in; (void)out_size; (void)ws_size;
  const float* x  = (const float*)d_in[0];
  const float* Wq = (const float*)d_in[1];
  const float* bq = (const float*)d_in[2];
  const float* Wk = (const float*)d_in[3];
  const float* bk = (const float*)d_in[4];
  const float* Wv = (const float*)d_in[5];
  const float* bv = (const float*)d_in[6];
  const float* Wo = (const float*)d_in[7];
  const float* bo = (const float*)d_in[8];
  float* out = (float*)d_out;
  char* ws = (char*)d_ws;

  size_t off = 0;
  auto take = [&](size_t bytes) { size_t r = off; off += (bytes + 255) & ~(size_t)255; return r; };
  const size_t WQKV_B = (size_t)3072 * 1024 * 2;        // 6 MB
  const size_t WT_B   = (size_t)1024 * 1024 * 2;        // 2 MB
  const size_t BIG_B  = (size_t)16384 * 1024 * 2;       // 32 MB (bf16 [16384][1024])
  const size_t KVT_B  = (size_t)64 * NCC * 4096 * 2;    // 32 MB bf16
  const size_t KS_B   = (size_t)64 * NCC * 64 * 4;      // 1 MB f32

  u16* WqkvT  = (u16*)(ws + take(WQKV_B));
  u16* WoT    = (u16*)(ws + take(WT_B));
  size_t shared_off = take(BIG_B);                      // xbf -> KVTc -> attn alias chain
  u16* xbf    = (u16*)(ws + shared_off);
  u16* KVTc   = (u16*)(ws + shared_off);
  u16* attn   = (u16*)(ws + shared_off);
  u16* Qb     = (u16*)(ws + take(BIG_B));               // Q|K|V contiguous (3 x 32 MB)
  u16* Kb     = (u16*)(ws + take(BIG_B));
  u16* Vb     = (u16*)(ws + take(BIG_B));
  u16* KVpreT = (u16*)(ws + take(KVT_B));
  float* Ksc  = (float*)(ws + take(KS_B));
  float* Kspre= (float*)(ws + take(KS_B));

  const dim3 blk(256);
  cvt_bf16_k<<<dim3(8192), blk, 0, stream>>>(x, xbf, 16384 * 1024 / 8);
  const dim3 gT(32, 32);
  transpose_cvt_k<<<gT, blk, 0, stream>>>(Wq, WqkvT);
  transpose_cvt_k<<<gT, blk, 0, stream>>>(Wk, WqkvT + (size_t)1024 * 1024);
  transpose_cvt_k<<<gT, blk, 0, stream>>>(Wv, WqkvT + (size_t)2048 * 1024);
  transpose_cvt_k<<<gT, blk, 0, stream>>>(Wo, WoT);

  // fused QKV: N=3072 -> Qb/Kb/Vb (contiguous segments)
  gemm97_k<true, false><<<dim3(24, 128), blk, 0, stream>>>(xbf, WqkvT, bq, bk, bv, Qb, 16384, 1024);

  const dim3 gC(NCC, Hh, 4);
  chunk_kv_k<<<gC, blk, 0, stream>>>(Kb, Vb, KVTc, Ksc);   // KVTc reuses xbf slot (xbf dead)
  prefix_k<<<dim3(64, 4), blk, 0, stream>>>(KVTc, Ksc, KVpreT, Kspre);
  chunk_out_k<<<gC, blk, 0, stream>>>(Qb, Kb, Vb, KVpreT, Kspre, attn);  // attn reuses slot

  gemm97_k<false, true><<<dim3(8, 128), blk, 0, stream>>>(attn, WoT, bo, NULL, NULL, out, 16384, 1024);
}

// Round 3
// 301.452 us; speedup vs baseline: 1.6309x; 1.1678x over previous
//
#include <hip/hip_runtime.h>
#include <stdint.h>

// ---------------------------------------------------------------------------
// LinearAttention (B=4, S=4096, HID=1024, H=16, D=64), chunked formulation.
// Round 3: 256x256 deep-pipelined GEMM (BK=64 as 2 k-half phases, counted
// vmcnt(4), T2 LDS XOR-swizzle, T5 setprio, XCD swizzle, LDS-staged epilogue).
// ---------------------------------------------------------------------------

#define DEVI __device__ __forceinline__

typedef __attribute__((ext_vector_type(8))) short bf16x8;
typedef __attribute__((ext_vector_type(4))) float f32x4;
typedef unsigned short u16;

DEVI u16 f2bf(float f) {
  union { float f; uint32_t u; } x; x.f = f;
  return (u16)((x.u + 0x7FFFu + ((x.u >> 16) & 1u)) >> 16);  // RNE
}
DEVI float bf2f(u16 u) {
  union { uint32_t u; float f; } x; x.u = ((uint32_t)u) << 16;
  return x.f;
}
DEVI f32x4 mfma16(bf16x8 a, bf16x8 b, f32x4 c) {
  return __builtin_amdgcn_mfma_f32_16x16x32_bf16(a, b, c, 0, 0, 0);
}

typedef __attribute__((address_space(3))) void* lds_vp;
typedef const __attribute__((address_space(1))) void* glb_vp;
DEVI void gload_lds16(const void* g, void* l) {
  __builtin_amdgcn_global_load_lds((glb_vp)g, (lds_vp)l, 16, 0, 0);
}

static constexpr int Ss  = 4096;
static constexpr int Hh  = 16;
static constexpr int CC  = 64;          // chunk length
static constexpr int NCC = Ss / CC;     // 64 chunks

// ---------------------------------------------------------------------------
// x (fp32) -> bf16, 8 elems/thread
// ---------------------------------------------------------------------------
__global__ __launch_bounds__(256) void cvt_bf16_k(const float* __restrict__ in,
                                                  u16* __restrict__ out, int n8) {
  const int i = blockIdx.x * 256 + threadIdx.x;
  if (i >= n8) return;
  const float4* p = (const float4*)(in + (size_t)i * 8);
  const float4 a = p[0], b = p[1];
  union { uint4 v; u16 s[8]; } u;
  u.s[0] = f2bf(a.x); u.s[1] = f2bf(a.y); u.s[2] = f2bf(a.z); u.s[3] = f2bf(a.w);
  u.s[4] = f2bf(b.x); u.s[5] = f2bf(b.y); u.s[6] = f2bf(b.z); u.s[7] = f2bf(b.w);
  ((uint4*)out)[i] = u.v;
}

// ---------------------------------------------------------------------------
// weight transpose + fp32->bf16:  out[n][k] = bf16(in[k][n]),  1024x1024
// ---------------------------------------------------------------------------
__global__ __launch_bounds__(256) void transpose_cvt_k(const float* __restrict__ in,
                                                       u16* __restrict__ out) {
  __shared__ float tl[32][33];
  const int tx = threadIdx.x & 31, ty = threadIdx.x >> 5;
  const int bx = blockIdx.x, by = blockIdx.y;
#pragma unroll
  for (int j = 0; j < 4; ++j)
    tl[ty + j * 8][tx] = in[(size_t)(by * 32 + ty + j * 8) * 1024 + bx * 32 + tx];
  __syncthreads();
#pragma unroll
  for (int j = 0; j < 4; ++j)
    out[(size_t)(bx * 32 + ty + j * 8) * 1024 + by * 32 + tx] = f2bf(tl[tx][ty + j * 8]);
}

// ---------------------------------------------------------------------------
// 256x256 deep-pipelined GEMM.  A bf16 [M][K], BT bf16 [N][K] (pre-transposed),
// out row stride fixed 1024.  512 threads = 8 waves (2M x 4N), acc[8][4].
// BK=64 = two K=32 half-phases; per phase: vmcnt(4)/barrier/stage-next/
// ds_read(swz)/lgkm0/setprio+32 MFMA.  LDS 128 KiB (2 buf x 2 khalf x A,B).
// FUSED: N=3072, segs {Q(elu+1,b0),K(elu+1,b1),V(none,b2)} -> bf16 seg arrays.
// else:  N=1024, bias b0 -> fp32 out.
// ---------------------------------------------------------------------------
template <bool FUSED, bool OUTF32>
__global__ __launch_bounds__(512, 2) void gemm256_k(const u16* __restrict__ A,
                                                    const u16* __restrict__ BT,
                                                    const float* __restrict__ b0,
                                                    const float* __restrict__ b1,
                                                    const float* __restrict__ b2,
                                                    void* __restrict__ out,
                                                    int M, int K) {
  __shared__ __attribute__((aligned(16))) u16 lds[65536];  // 128 KiB
  const int t = threadIdx.x, lane = t & 63, w = t >> 6;
  const int wm = w >> 2, wn = w & 3;

  // XCD-aware bijective swizzle (nwg % 8 == 0 for our grids)
  const int nx = gridDim.x;
  const int nwg = nx * gridDim.y;
  const int bid = blockIdx.y * nx + blockIdx.x;
  const int swz = (bid & 7) * (nwg >> 3) + (bid >> 3);
  const int bx = swz % nx, by = swz / nx;
  const int m0 = by * 256, n0 = bx * 256;

  const u16* gA = A + (size_t)m0 * K;
  const u16* gB = BT + (size_t)n0 * K;

  // staging: slot j covers row (t>>2)+j*128, 16B chunk (t&3); logical k-chunk
  // is XOR-swizzled so the linear LDS dest reads back swizzled (rule #21).
  const int sr  = t >> 2;
  const int sc  = (t & 3) ^ ((sr >> 1) & 3);   // same for both slots (row+128 preserves (row>>1)&3)
  auto stage = [&](const u16* gm, u16* lr, int kofs) {
    gload_lds16(gm + (size_t)sr * K + kofs + sc * 8, lr + t * 8);
    gload_lds16(gm + (size_t)(sr + 128) * K + kofs + sc * 8, lr + 4096 + t * 8);
  };

  f32x4 acc[8][4];
#pragma unroll
  for (int i = 0; i < 8; ++i)
#pragma unroll
    for (int j = 0; j < 4; ++j) acc[i][j] = f32x4{0.f, 0.f, 0.f, 0.f};

  // prologue: stage tile 0 (k-half0 then k-half1) -> 8 outstanding loads
  stage(gA, lds, 0);          stage(gB, lds + 32768, 0);
  stage(gA, lds + 8192, 32);  stage(gB, lds + 40960, 32);

  const int fr = lane & 15, kq = lane >> 4;
  const int nk = K >> 6;
  for (int kt = 0; kt < nk; ++kt) {
    const int buf = kt & 1;
    u16* Ab = lds + buf * 16384;
    u16* Bb = lds + 32768 + buf * 16384;
    u16* An = lds + (buf ^ 1) * 16384;
    u16* Bn = lds + 32768 + (buf ^ 1) * 16384;
    const bool pf = (kt + 1 < nk);
    const int kon = (kt + 1) << 6;
#pragma unroll
    for (int ph = 0; ph < 2; ++ph) {
      if (pf || ph == 0) asm volatile("s_waitcnt vmcnt(4)" ::: "memory");
      else               asm volatile("s_waitcnt vmcnt(0)" ::: "memory");
      __builtin_amdgcn_s_barrier();
      asm volatile("" ::: "memory");
      if (pf) {
        stage(gA, An + ph * 8192, kon + ph * 32);
        stage(gB, Bn + ph * 8192, kon + ph * 32);
      }
      const u16* Ar = Ab + ph * 8192;
      const u16* Br = Bb + ph * 8192;
      bf16x8 af[8], bg[4];
#pragma unroll
      for (int fi = 0; fi < 8; ++fi) {
        const int row = wm * 128 + fi * 16 + fr;
        af[fi] = *(const bf16x8*)(Ar + row * 32 + ((kq ^ ((row >> 1) & 3)) << 3));
      }
#pragma unroll
      for (int fj = 0; fj < 4; ++fj) {
        const int row = wn * 64 + fj * 16 + fr;
        bg[fj] = *(const bf16x8*)(Br + row * 32 + ((kq ^ ((row >> 1) & 3)) << 3));
      }
      asm volatile("s_waitcnt lgkmcnt(0)" ::: "memory");
      __builtin_amdgcn_sched_barrier(0);
      __builtin_amdgcn_s_setprio(1);
#pragma unroll
      for (int fi = 0; fi < 8; ++fi)
#pragma unroll
        for (int fj = 0; fj < 4; ++fj)
          acc[fi][fj] = mfma16(af[fi], bg[fj], acc[fi][fj]);
      __builtin_amdgcn_s_setprio(0);
      __builtin_amdgcn_sched_barrier(0);
    }
  }

  // ---------------- epilogue: LDS-staged coalesced stores ----------------
  const int rowg = (lane >> 4) * 4;
  if constexpr (!OUTF32) {
    // bf16 path: LDS as [256][256] u16, 16B-chunk XOR swizzle (row>>2)&31
    __syncthreads();
    const int seg  = FUSED ? (n0 >> 10) : 0;
    const int lcol0 = FUSED ? (n0 & 1023) : n0;
    const float* bp = b0;
    if constexpr (FUSED) bp = (seg == 0) ? b0 : (seg == 1) ? b1 : b2;
#pragma unroll
    for (int fj = 0; fj < 4; ++fj) {
      const int col = wn * 64 + fj * 16 + fr;
      const float bv = bp[lcol0 + col];
#pragma unroll
      for (int fi = 0; fi < 8; ++fi) {
#pragma unroll
        for (int rr = 0; rr < 4; ++rr) {
          const int row = wm * 128 + fi * 16 + rowg + rr;
          float v = acc[fi][fj][rr] + bv;
          if (FUSED && seg < 2) v = (v > 0.f) ? (v + 1.f) : __expf(v);
          lds[row * 256 + (((col >> 3) ^ ((row >> 2) & 31)) << 3) + (col & 7)] = f2bf(v);
        }
      }
    }
    __syncthreads();
    u16* outp = (u16*)out + (size_t)seg * M * 1024 + (size_t)m0 * 1024 + lcol0;
#pragma unroll
    for (int it = 0; it < 16; ++it) {
      const int g = it * 512 + t;
      const int row = g >> 5, c16 = g & 31;
      const uint4 v = *(const uint4*)&lds[row * 256 + ((c16 ^ ((row >> 2) & 31)) << 3)];
      *(uint4*)(outp + (size_t)row * 1024 + c16 * 8) = v;
    }
  } else {
    // fp32 path: two row-half passes, LDS as [128][256] f32, chunk swizzle
    float* flds = (float*)lds;
#pragma unroll
    for (int pass = 0; pass < 2; ++pass) {
      __syncthreads();
      if (wm == pass) {
#pragma unroll
        for (int fj = 0; fj < 4; ++fj) {
          const int col = wn * 64 + fj * 16 + fr;
          const float bv = b0[n0 + col];
#pragma unroll
          for (int fi = 0; fi < 8; ++fi) {
#pragma unroll
            for (int rr = 0; rr < 4; ++rr) {
              const int rl = fi * 16 + rowg + rr;
              flds[rl * 256 + (((col >> 2) ^ ((rl >> 2) & 63)) << 2) + (col & 3)] =
                  acc[fi][fj][rr] + bv;
            }
          }
        }
      }
      __syncthreads();
      float* outp = (float*)out + (size_t)(m0 + pass * 128) * 1024 + n0;
#pragma unroll
      for (int it = 0; it < 16; ++it) {
        const int g = it * 512 + t;
        const int row = g >> 6, c16 = g & 63;
        const uint4 v = *(const uint4*)&flds[row * 256 + ((c16 ^ ((row >> 2) & 63)) << 2)];
        *(uint4*)(outp + (size_t)row * 1024 + c16 * 4) = v;
      }
    }
  }
}

// ---------------------------------------------------------------------------
// per-chunk KVT_c[e][d] = sum_i V[i][e]*K[i][d]  (bf16 out), Ks_c[d] (f32)
// grid (NCC, H, B), 256 threads
// ---------------------------------------------------------------------------
__global__ __launch_bounds__(256) void chunk_kv_k(const u16* __restrict__ Kb,
                                                  const u16* __restrict__ Vb,
                                                  u16* __restrict__ KVTc,
                                                  float* __restrict__ Ksc) {
  const int c = blockIdx.x, h = blockIdx.y, b = blockIdx.z;
  __shared__ u16 Kl[64][72], Vl[64][72];
  const int t = threadIdx.x;
  {
    const int i = t >> 2, c0 = (t & 3) * 16;
    const size_t g = ((size_t)(b * Ss + c * CC + i)) * 1024 + h * 64 + c0;
    const uint4* kp = (const uint4*)(Kb + g);
    uint4* kd = (uint4*)&Kl[i][c0]; kd[0] = kp[0]; kd[1] = kp[1];
    const uint4* vp = (const uint4*)(Vb + g);
    uint4* vd = (uint4*)&Vl[i][c0]; vd[0] = vp[0]; vd[1] = vp[1];
  }
  __syncthreads();
  const int e = t >> 2, d0 = (t & 3) * 16;
  float acc[16];
#pragma unroll
  for (int j = 0; j < 16; ++j) acc[j] = 0.f;
  for (int i = 0; i < 64; ++i) {
    const float v = bf2f(Vl[i][e]);
    const bf16x8 k0 = *(const bf16x8*)&Kl[i][d0];
    const bf16x8 k1 = *(const bf16x8*)&Kl[i][d0 + 8];
#pragma unroll
    for (int j = 0; j < 8; ++j) acc[j]     += v * bf2f((u16)k0[j]);
#pragma unroll
    for (int j = 0; j < 8; ++j) acc[j + 8] += v * bf2f((u16)k1[j]);
  }
  const size_t base = ((size_t)((b * Hh + h) * NCC + c)) * 4096 + (size_t)e * 64 + d0;
#pragma unroll
  for (int j = 0; j < 16; ++j) KVTc[base + j] = f2bf(acc[j]);
  if (t < 64) {
    float s = 0.f;
    for (int i = 0; i < 64; ++i) s += bf2f(Kl[i][t]);
    Ksc[((size_t)((b * Hh + h) * NCC + c)) * 64 + t] = s;
  }
}

// ---------------------------------------------------------------------------
// exclusive prefix over chunks per (b,h).  grid (64, 16): y splits the 4096
// KV elements into 16 x 256.
// ---------------------------------------------------------------------------
__global__ __launch_bounds__(256) void prefix_k(const u16* __restrict__ KVTc,
                                                const float* __restrict__ Ksc,
                                                u16* __restrict__ KVpreT,
                                                float* __restrict__ Kspre) {
  const int bh = blockIdx.x, eg = blockIdx.y;
  const int t = threadIdx.x;
  float run = 0.f;
  float rk = 0.f;
  for (int c = 0; c < NCC; ++c) {
    const size_t idx = ((size_t)(bh * NCC + c)) * 4096 + (size_t)eg * 256 + t;
    KVpreT[idx] = f2bf(run);
    run += bf2f(KVTc[idx]);
    if (eg == 15 && t < 64) {
      const size_t kb = ((size_t)(bh * NCC + c)) * 64 + t;
      Kspre[kb] = rk;
      rk += Ksc[kb];
    }
  }
}

// ---------------------------------------------------------------------------
// per-(b,h,c) chunk output.  grid (NCC, H, B), 256 threads (4 waves).
// ---------------------------------------------------------------------------
__global__ __launch_bounds__(256) void chunk_out_k(const u16* __restrict__ Qb,
                                                   const u16* __restrict__ Kb,
                                                   const u16* __restrict__ Vb,
                                                   const u16* __restrict__ KVpreT,
                                                   const float* __restrict__ Kspre,
                                                   u16* __restrict__ attn) {
  const int c = blockIdx.x, h = blockIdx.y, b = blockIdx.z;
  const int bh = b * Hh + h;
  __shared__ u16 Ql[64][72], Kl[64][72], VT[64][72], Pl[64][72];
  __shared__ float den[64];
  const int t = threadIdx.x, lane = t & 63, w = t >> 6;

  {
    const int i = t >> 2, c0 = (t & 3) * 16;
    const size_t g = ((size_t)(b * Ss + c * CC + i)) * 1024 + h * 64 + c0;
    const uint4* qp = (const uint4*)(Qb + g);
    uint4* qd = (uint4*)&Ql[i][c0]; qd[0] = qp[0]; qd[1] = qp[1];
    const uint4* kp = (const uint4*)(Kb + g);
    uint4* kd = (uint4*)&Kl[i][c0]; kd[0] = kp[0]; kd[1] = kp[1];
    const u16* vp = Vb + g;
#pragma unroll
    for (int j = 0; j < 16; ++j) VT[c0 + j][i] = vp[j];  // transpose V -> [e][i]
  }
  __syncthreads();

  // Phase A: S = Q K^T for rows w*16..+15, all 64 cols
  f32x4 sacc[4];
#pragma unroll
  for (int fj = 0; fj < 4; ++fj) sacc[fj] = f32x4{0.f, 0.f, 0.f, 0.f};
#pragma unroll
  for (int kd = 0; kd < 2; ++kd) {
    const bf16x8 aq = *(const bf16x8*)&Ql[w * 16 + (lane & 15)][kd * 32 + (lane >> 4) * 8];
#pragma unroll
    for (int fj = 0; fj < 4; ++fj) {
      const bf16x8 bk = *(const bf16x8*)&Kl[fj * 16 + (lane & 15)][kd * 32 + (lane >> 4) * 8];
      sacc[fj] = mfma16(aq, bk, sacc[fj]);
    }
  }
  float rowsum[4] = {0.f, 0.f, 0.f, 0.f};
#pragma unroll
  for (int fj = 0; fj < 4; ++fj) {
#pragma unroll
    for (int rr = 0; rr < 4; ++rr) {
      const int i_loc = w * 16 + (lane >> 4) * 4 + rr;
      const int j_loc = fj * 16 + (lane & 15);
      const float v = (j_loc <= i_loc) ? sacc[fj][rr] : 0.f;
      Pl[i_loc][j_loc] = f2bf(v);
      rowsum[rr] += v;
    }
  }
#pragma unroll
  for (int off = 1; off < 16; off <<= 1) {
#pragma unroll
    for (int rr = 0; rr < 4; ++rr) rowsum[rr] += __shfl_xor(rowsum[rr], off, 64);
  }
  if ((lane & 15) == 0) {
#pragma unroll
    for (int rr = 0; rr < 4; ++rr) den[w * 16 + (lane >> 4) * 4 + rr] = rowsum[rr];
  }
  __syncthreads();
  if (t < 64) {
    const float* ksp = Kspre + ((size_t)(bh * NCC + c)) * 64;
    float s = den[t] + 1e-6f;
    for (int d2 = 0; d2 < 64; ++d2) s += bf2f(Ql[t][d2]) * ksp[d2];
    den[t] = s;
  }
  __syncthreads();

  // Phase B: O = Q @ KVpre + P @ V
  f32x4 oacc[4];
#pragma unroll
  for (int fj = 0; fj < 4; ++fj) oacc[fj] = f32x4{0.f, 0.f, 0.f, 0.f};
  const u16* kvb = KVpreT + ((size_t)(bh * NCC + c)) * 4096;
#pragma unroll
  for (int ks2 = 0; ks2 < 2; ++ks2) {
    const bf16x8 aq = *(const bf16x8*)&Ql[w * 16 + (lane & 15)][ks2 * 32 + (lane >> 4) * 8];
#pragma unroll
    for (int fj = 0; fj < 4; ++fj) {
      const bf16x8 bv =
          *(const bf16x8*)(kvb + (size_t)(fj * 16 + (lane & 15)) * 64 + ks2 * 32 + (lane >> 4) * 8);
      oacc[fj] = mfma16(aq, bv, oacc[fj]);
    }
  }
#pragma unroll
  for (int ks3 = 0; ks3 < 2; ++ks3) {
    const bf16x8 ap = *(const bf16x8*)&Pl[w * 16 + (lane & 15)][ks3 * 32 + (lane >> 4) * 8];
#pragma unroll
    for (int fj = 0; fj < 4; ++fj) {
      const bf16x8 bv = *(const bf16x8*)&VT[fj * 16 + (lane & 15)][ks3 * 32 + (lane >> 4) * 8];
      oacc[fj] = mfma16(ap, bv, oacc[fj]);
    }
  }
#pragma unroll
  for (int fj = 0; fj < 4; ++fj) {
#pragma unroll
    for (int rr = 0; rr < 4; ++rr) {
      const int i_loc = w * 16 + (lane >> 4) * 4 + rr;
      const int e = fj * 16 + (lane & 15);
      const float v = oacc[fj][rr] / den[i_loc];
      attn[((size_t)(b * Ss + c * CC + i_loc)) * 1024 + h * 64 + e] = f2bf(v);
    }
  }
}

// ---------------------------------------------------------------------------
extern "C" void kernel_launch(void* const* d_in, const int* in_sizes, int n_in,
                              void* d_out, int out_size, void* d_ws, size_t ws_size,
                              hipStream_t stream) {
  (void)in_sizes; (void)n_in; (void)out_size; (void)ws_size;
  const float* x  = (const float*)d_in[0];
  const float* Wq = (const float*)d_in[1];
  const float* bq = (const float*)d_in[2];
  const float* Wk = (const float*)d_in[3];
  const float* bk = (const float*)d_in[4];
  const float* Wv = (const float*)d_in[5];
  const float* bv = (const float*)d_in[6];
  const float* Wo = (const float*)d_in[7];
  const float* bo = (const float*)d_in[8];
  float* out = (float*)d_out;
  char* ws = (char*)d_ws;

  size_t off = 0;
  auto take = [&](size_t bytes) { size_t r = off; off += (bytes + 255) & ~(size_t)255; return r; };
  const size_t WQKV_B = (size_t)3072 * 1024 * 2;        // 6 MB
  const size_t WT_B   = (size_t)1024 * 1024 * 2;        // 2 MB
  const size_t BIG_B  = (size_t)16384 * 1024 * 2;       // 32 MB
  const size_t KVT_B  = (size_t)64 * NCC * 4096 * 2;    // 32 MB bf16
  const size_t KS_B   = (size_t)64 * NCC * 64 * 4;      // 1 MB f32

  u16* WqkvT  = (u16*)(ws + take(WQKV_B));
  u16* WoT    = (u16*)(ws + take(WT_B));
  size_t shared_off = take(BIG_B);                      // xbf -> KVTc -> attn alias chain
  u16* xbf    = (u16*)(ws + shared_off);
  u16* KVTc   = (u16*)(ws + shared_off);
  u16* attn   = (u16*)(ws + shared_off);
  u16* Qb     = (u16*)(ws + take(BIG_B));               // Q|K|V contiguous (3 x 32 MB)
  u16* Kb     = (u16*)(ws + take(BIG_B));
  u16* Vb     = (u16*)(ws + take(BIG_B));
  u16* KVpreT = (u16*)(ws + take(KVT_B));
  float* Ksc  = (float*)(ws + take(KS_B));
  float* Kspre= (float*)(ws + take(KS_B));

  const dim3 blk(256);
  cvt_bf16_k<<<dim3(8192), blk, 0, stream>>>(x, xbf, 16384 * 1024 / 8);
  const dim3 gT(32, 32);
  transpose_cvt_k<<<gT, blk, 0, stream>>>(Wq, WqkvT);
  transpose_cvt_k<<<gT, blk, 0, stream>>>(Wk, WqkvT + (size_t)1024 * 1024);
  transpose_cvt_k<<<gT, blk, 0, stream>>>(Wv, WqkvT + (size_t)2048 * 1024);
  transpose_cvt_k<<<gT, blk, 0, stream>>>(Wo, WoT);

  // fused QKV: N=3072 -> Qb/Kb/Vb (contiguous segments); grid (N/256, M/256)
  gemm256_k<true, false><<<dim3(12, 64), dim3(512), 0, stream>>>(
      xbf, WqkvT, bq, bk, bv, Qb, 16384, 1024);

  const dim3 gC(NCC, Hh, 4);
  chunk_kv_k<<<gC, blk, 0, stream>>>(Kb, Vb, KVTc, Ksc);   // KVTc reuses xbf slot
  prefix_k<<<dim3(64, 16), blk, 0, stream>>>(KVTc, Ksc, KVpreT, Kspre);
  chunk_out_k<<<gC, blk, 0, stream>>>(Qb, Kb, Vb, KVpreT, Kspre, attn);

  gemm256_k<false, true><<<dim3(4, 64), dim3(512), 0, stream>>>(
      attn, WoT, bo, NULL, NULL, out, 16384, 1024);
}

// Round 4
// 267.372 us; speedup vs baseline: 1.8388x; 1.1275x over previous
//
#include <hip/hip_runtime.h>
#include <stdint.h>

// ---------------------------------------------------------------------------
// LinearAttention (B=4, S=4096, HID=1024, H=16, D=64), chunked formulation.
// Round 4: 256x256 GEMM with 4 fine phases/K-tile (16 MFMA each), region-
// granular staging (A|B x khalf), counted vmcnt(4), 2 barriers/K-tile,
// T2 swizzle + T5 setprio.  chunk_kv -> MFMA; den parallelized; prefix vec.
// ---------------------------------------------------------------------------

#define DEVI __device__ __forceinline__

typedef __attribute__((ext_vector_type(8))) short bf16x8;
typedef __attribute__((ext_vector_type(4))) float f32x4;
typedef unsigned short u16;

DEVI u16 f2bf(float f) {
  union { float f; uint32_t u; } x; x.f = f;
  return (u16)((x.u + 0x7FFFu + ((x.u >> 16) & 1u)) >> 16);  // RNE
}
DEVI float bf2f(u16 u) {
  union { uint32_t u; float f; } x; x.u = ((uint32_t)u) << 16;
  return x.f;
}
DEVI f32x4 mfma16(bf16x8 a, bf16x8 b, f32x4 c) {
  return __builtin_amdgcn_mfma_f32_16x16x32_bf16(a, b, c, 0, 0, 0);
}

typedef __attribute__((address_space(3))) void* lds_vp;
typedef const __attribute__((address_space(1))) void* glb_vp;
DEVI void gload_lds16(const void* g, void* l) {
  __builtin_amdgcn_global_load_lds((glb_vp)g, (lds_vp)l, 16, 0, 0);
}

static constexpr int Ss  = 4096;
static constexpr int Hh  = 16;
static constexpr int CC  = 64;          // chunk length
static constexpr int NCC = Ss / CC;     // 64 chunks

// ---------------------------------------------------------------------------
// x (fp32) -> bf16, 8 elems/thread
// ---------------------------------------------------------------------------
__global__ __launch_bounds__(256) void cvt_bf16_k(const float* __restrict__ in,
                                                  u16* __restrict__ out, int n8) {
  const int i = blockIdx.x * 256 + threadIdx.x;
  if (i >= n8) return;
  const float4* p = (const float4*)(in + (size_t)i * 8);
  const float4 a = p[0], b = p[1];
  union { uint4 v; u16 s[8]; } u;
  u.s[0] = f2bf(a.x); u.s[1] = f2bf(a.y); u.s[2] = f2bf(a.z); u.s[3] = f2bf(a.w);
  u.s[4] = f2bf(b.x); u.s[5] = f2bf(b.y); u.s[6] = f2bf(b.z); u.s[7] = f2bf(b.w);
  ((uint4*)out)[i] = u.v;
}

// ---------------------------------------------------------------------------
// weight transpose + fp32->bf16:  out[n][k] = bf16(in[k][n]),  1024x1024
// ---------------------------------------------------------------------------
__global__ __launch_bounds__(256) void transpose_cvt_k(const float* __restrict__ in,
                                                       u16* __restrict__ out) {
  __shared__ float tl[32][33];
  const int tx = threadIdx.x & 31, ty = threadIdx.x >> 5;
  const int bx = blockIdx.x, by = blockIdx.y;
#pragma unroll
  for (int j = 0; j < 4; ++j)
    tl[ty + j * 8][tx] = in[(size_t)(by * 32 + ty + j * 8) * 1024 + bx * 32 + tx];
  __syncthreads();
#pragma unroll
  for (int j = 0; j < 4; ++j)
    out[(size_t)(bx * 32 + ty + j * 8) * 1024 + by * 32 + tx] = f2bf(tl[tx][ty + j * 8]);
}

// ---------------------------------------------------------------------------
// 256x256 deep-pipelined GEMM, 4 fine phases per K-tile (BK=64).
// A bf16 [M][K], BT bf16 [N][K].  512 threads = 8 waves (2M x 4N), acc[8][4].
// Region = (A|B, khalf) = 256 rows x 32 k = 16 KB, staged with 2 gloads/thr.
// Phase p of kt:  p0: vmcnt(4)+bar, stage A-kh0(kt+1), read A(kk0)+B(fj01,kk0),
//   16 MFMA;  p1: stage B-kh0(kt+1), read B(fj23,kk0), 16 MFMA;
//   p2: vmcnt(4|0)+bar, stage A-kh1, read A(kk1)+B(fj01,kk1), 16 MFMA;
//   p3: stage B-kh1, read B(fj23,kk1), 16 MFMA.
// Loads retire in order -> vmcnt(4) proves "everything but newest 4 landed".
// ---------------------------------------------------------------------------
template <bool FUSED, bool OUTF32>
__global__ __launch_bounds__(512, 2) void gemm256_k(const u16* __restrict__ A,
                                                    const u16* __restrict__ BT,
                                                    const float* __restrict__ b0,
                                                    const float* __restrict__ b1,
                                                    const float* __restrict__ b2,
                                                    void* __restrict__ out,
                                                    int M, int K) {
  __shared__ __attribute__((aligned(16))) u16 lds[65536];  // 128 KiB
  const int t = threadIdx.x, lane = t & 63, w = t >> 6;
  const int wm = w >> 2, wn = w & 3;

  // XCD-aware bijective swizzle (nwg % 8 == 0 for our grids)
  const int nx = gridDim.x;
  const int nwg = nx * gridDim.y;
  const int bid = blockIdx.y * nx + blockIdx.x;
  const int swz = (bid & 7) * (nwg >> 3) + (bid >> 3);
  const int bx = swz % nx, by = swz / nx;
  const int m0 = by * 256, n0 = bx * 256;

  const u16* gA = A + (size_t)m0 * K;
  const u16* gB = BT + (size_t)n0 * K;

  // staging: region 256 rows x 32 k; thread covers rows t>>2 and (t>>2)+128,
  // 16B chunk (t&3); global k-chunk pre-XOR-swizzled (rule #21).
  const int sr = t >> 2;
  const int sc = (t & 3) ^ ((sr >> 1) & 3);
  auto stage = [&](const u16* gm, u16* dst, int kof) {
    gload_lds16(gm + (size_t)sr * K + kof + sc * 8, dst + t * 8);
    gload_lds16(gm + (size_t)(sr + 128) * K + kof + sc * 8, dst + 4096 + t * 8);
  };

  f32x4 acc[8][4];
#pragma unroll
  for (int i = 0; i < 8; ++i)
#pragma unroll
    for (int j = 0; j < 4; ++j) acc[i][j] = f32x4{0.f, 0.f, 0.f, 0.f};

  // prologue: tile 0 regions in loop order A0,B0,A1,B1
  stage(gA, lds, 0);          stage(gB, lds + 32768, 0);
  stage(gA, lds + 8192, 32);  stage(gB, lds + 40960, 32);

  const int fr = lane & 15, kq = lane >> 4;
  const int rdko = ((kq ^ ((fr >> 1) & 3)) << 3);  // swizzled k-chunk offset (u16)
  const int arow0 = wm * 128 + fr;
  const int brow0 = wn * 64 + fr;

  const int nk = K >> 6;
  for (int kt = 0; kt < nk; ++kt) {
    const int buf = kt & 1;
    u16* Ax = lds + buf * 16384;
    u16* Bx = lds + 32768 + buf * 16384;
    u16* Ay = lds + (buf ^ 1) * 16384;
    u16* By = lds + 32768 + (buf ^ 1) * 16384;
    const bool pf = (kt + 1 < nk);
    const int kon = (kt + 1) << 6;
    bf16x8 af[8], bg0, bg1;

#pragma unroll
    for (int half = 0; half < 2; ++half) {
      u16* Axh = Ax + half * 8192;
      u16* Bxh = Bx + half * 8192;
      // ---- phase 2*half ----
      if (half == 0 || pf) asm volatile("s_waitcnt vmcnt(4)" ::: "memory");
      else                 asm volatile("s_waitcnt vmcnt(0)" ::: "memory");
      __builtin_amdgcn_s_barrier();
      if (pf) stage(gA, Ay + half * 8192, kon + half * 32);
#pragma unroll
      for (int fi = 0; fi < 8; ++fi)
        af[fi] = *(const bf16x8*)(Axh + (arow0 + fi * 16) * 32 + rdko);
      bg0 = *(const bf16x8*)(Bxh + brow0 * 32 + rdko);
      bg1 = *(const bf16x8*)(Bxh + (brow0 + 16) * 32 + rdko);
      asm volatile("s_waitcnt lgkmcnt(0)" ::: "memory");
      __builtin_amdgcn_sched_barrier(0);
      __builtin_amdgcn_s_setprio(1);
#pragma unroll
      for (int fi = 0; fi < 8; ++fi) {
        acc[fi][0] = mfma16(af[fi], bg0, acc[fi][0]);
        acc[fi][1] = mfma16(af[fi], bg1, acc[fi][1]);
      }
      __builtin_amdgcn_s_setprio(0);
      __builtin_amdgcn_sched_barrier(0);
      // ---- phase 2*half+1 (no barrier needed: different LDS buffer) ----
      if (pf) stage(gB, By + half * 8192, kon + half * 32);
      bg0 = *(const bf16x8*)(Bxh + (brow0 + 32) * 32 + rdko);
      bg1 = *(const bf16x8*)(Bxh + (brow0 + 48) * 32 + rdko);
      asm volatile("s_waitcnt lgkmcnt(0)" ::: "memory");
      __builtin_amdgcn_sched_barrier(0);
      __builtin_amdgcn_s_setprio(1);
#pragma unroll
      for (int fi = 0; fi < 8; ++fi) {
        acc[fi][2] = mfma16(af[fi], bg0, acc[fi][2]);
        acc[fi][3] = mfma16(af[fi], bg1, acc[fi][3]);
      }
      __builtin_amdgcn_s_setprio(0);
      __builtin_amdgcn_sched_barrier(0);
    }
  }

  // ---------------- epilogue: LDS-staged coalesced stores ----------------
  const int rowg = (lane >> 4) * 4;
  if constexpr (!OUTF32) {
    __syncthreads();
    const int seg  = FUSED ? (n0 >> 10) : 0;
    const int lcol0 = FUSED ? (n0 & 1023) : n0;
    const float* bp = b0;
    if constexpr (FUSED) bp = (seg == 0) ? b0 : (seg == 1) ? b1 : b2;
#pragma unroll
    for (int fj = 0; fj < 4; ++fj) {
      const int col = wn * 64 + fj * 16 + fr;
      const float bv = bp[lcol0 + col];
#pragma unroll
      for (int fi = 0; fi < 8; ++fi) {
#pragma unroll
        for (int rr = 0; rr < 4; ++rr) {
          const int row = wm * 128 + fi * 16 + rowg + rr;
          float v = acc[fi][fj][rr] + bv;
          if (FUSED && seg < 2) v = (v > 0.f) ? (v + 1.f) : __expf(v);
          lds[row * 256 + (((col >> 3) ^ ((row >> 2) & 31)) << 3) + (col & 7)] = f2bf(v);
        }
      }
    }
    __syncthreads();
    u16* outp = (u16*)out + (size_t)seg * M * 1024 + (size_t)m0 * 1024 + lcol0;
#pragma unroll
    for (int it = 0; it < 16; ++it) {
      const int g = it * 512 + t;
      const int row = g >> 5, c16 = g & 31;
      const uint4 v = *(const uint4*)&lds[row * 256 + ((c16 ^ ((row >> 2) & 31)) << 3)];
      *(uint4*)(outp + (size_t)row * 1024 + c16 * 8) = v;
    }
  } else {
    float* flds = (float*)lds;
#pragma unroll
    for (int pass = 0; pass < 2; ++pass) {
      __syncthreads();
      if (wm == pass) {
#pragma unroll
        for (int fj = 0; fj < 4; ++fj) {
          const int col = wn * 64 + fj * 16 + fr;
          const float bv = b0[n0 + col];
#pragma unroll
          for (int fi = 0; fi < 8; ++fi) {
#pragma unroll
            for (int rr = 0; rr < 4; ++rr) {
              const int rl = fi * 16 + rowg + rr;
              flds[rl * 256 + (((col >> 2) ^ ((rl >> 2) & 63)) << 2) + (col & 3)] =
                  acc[fi][fj][rr] + bv;
            }
          }
        }
      }
      __syncthreads();
      float* outp = (float*)out + (size_t)(m0 + pass * 128) * 1024 + n0;
#pragma unroll
      for (int it = 0; it < 16; ++it) {
        const int g = it * 512 + t;
        const int row = g >> 6, c16 = g & 63;
        const uint4 v = *(const uint4*)&flds[row * 256 + ((c16 ^ ((row >> 2) & 63)) << 2)];
        *(uint4*)(outp + (size_t)row * 1024 + c16 * 4) = v;
      }
    }
  }
}

// ---------------------------------------------------------------------------
// per-chunk KVT_c[e][d] = sum_i V[i][e]*K[i][d]  (bf16 out, via MFMA),
// Ks_c[d] = sum_i K[i][d] (f32).  grid (NCC, H, B), 256 threads (4 waves).
// ---------------------------------------------------------------------------
__global__ __launch_bounds__(256) void chunk_kv_k(const u16* __restrict__ Kb,
                                                  const u16* __restrict__ Vb,
                                                  u16* __restrict__ KVTc,
                                                  float* __restrict__ Ksc) {
  const int c = blockIdx.x, h = blockIdx.y, b = blockIdx.z;
  __shared__ u16 KT[64][72], VT[64][72];   // transposed: [d][i] / [e][i]
  const int t = threadIdx.x, lane = t & 63, w = t >> 6;
  {
    const int i = t >> 2, c0 = (t & 3) * 16;
    const size_t g = ((size_t)(b * Ss + c * CC + i)) * 1024 + h * 64 + c0;
    const u16* kp = Kb + g;
    const u16* vp = Vb + g;
#pragma unroll
    for (int j = 0; j < 16; ++j) { KT[c0 + j][i] = kp[j]; VT[c0 + j][i] = vp[j]; }
  }
  __syncthreads();
  // D[e][d] = sum_i VT[e][i] * KT[d][i]; wave w owns e rows w*16..+15
  f32x4 acc[4];
#pragma unroll
  for (int j = 0; j < 4; ++j) acc[j] = f32x4{0.f, 0.f, 0.f, 0.f};
  const int fr = lane & 15, kq = (lane >> 4) * 8;
#pragma unroll
  for (int kk = 0; kk < 2; ++kk) {
    const bf16x8 av = *(const bf16x8*)&VT[w * 16 + fr][kk * 32 + kq];
#pragma unroll
    for (int fj = 0; fj < 4; ++fj) {
      const bf16x8 bk = *(const bf16x8*)&KT[fj * 16 + fr][kk * 32 + kq];
      acc[fj] = mfma16(av, bk, acc[fj]);
    }
  }
  const size_t base = ((size_t)((b * Hh + h) * NCC + c)) * 4096;
#pragma unroll
  for (int fj = 0; fj < 4; ++fj)
#pragma unroll
    for (int rr = 0; rr < 4; ++rr) {
      const int e = w * 16 + (lane >> 4) * 4 + rr;
      const int d = fj * 16 + fr;
      KVTc[base + (size_t)e * 64 + d] = f2bf(acc[fj][rr]);
    }
  if (t < 64) {
    float s = 0.f;
#pragma unroll
    for (int ii = 0; ii < 8; ++ii) {
      const bf16x8 kv = *(const bf16x8*)&KT[t][ii * 8];
#pragma unroll
      for (int j = 0; j < 8; ++j) s += bf2f((u16)kv[j]);
    }
    Ksc[((size_t)((b * Hh + h) * NCC + c)) * 64 + t] = s;
  }
}

// ---------------------------------------------------------------------------
// exclusive prefix over chunks per (b,h).  grid (64, 4); thread owns 4
// consecutive elements (uint2 loads/stores).
// ---------------------------------------------------------------------------
__global__ __launch_bounds__(256) void prefix_k(const u16* __restrict__ KVTc,
                                                const float* __restrict__ Ksc,
                                                u16* __restrict__ KVpreT,
                                                float* __restrict__ Kspre) {
  const int bh = blockIdx.x, eg = blockIdx.y;
  const int t = threadIdx.x;
  const int e4 = eg * 1024 + t * 4;
  const u16* src = KVTc + (size_t)bh * NCC * 4096 + e4;
  u16* dst = KVpreT + (size_t)bh * NCC * 4096 + e4;
  const float* kss = Ksc + (size_t)bh * NCC * 64 + t;
  float* ksd = Kspre + (size_t)bh * NCC * 64 + t;
  float run[4] = {0.f, 0.f, 0.f, 0.f};
  float rk = 0.f;
  for (int c = 0; c < NCC; ++c) {
    union { uint2 v; u16 s[4]; } in, ov;
    in.v = *(const uint2*)(src + (size_t)c * 4096);
#pragma unroll
    for (int j = 0; j < 4; ++j) { ov.s[j] = f2bf(run[j]); run[j] += bf2f(in.s[j]); }
    *(uint2*)(dst + (size_t)c * 4096) = ov.v;
    if (eg == 0 && t < 64) { ksd[(size_t)c * 64] = rk; rk += kss[(size_t)c * 64]; }
  }
}

// ---------------------------------------------------------------------------
// per-(b,h,c) chunk output.  grid (NCC, H, B), 256 threads (4 waves).
// ---------------------------------------------------------------------------
__global__ __launch_bounds__(256) void chunk_out_k(const u16* __restrict__ Qb,
                                                   const u16* __restrict__ Kb,
                                                   const u16* __restrict__ Vb,
                                                   const u16* __restrict__ KVpreT,
                                                   const float* __restrict__ Kspre,
                                                   u16* __restrict__ attn) {
  const int c = blockIdx.x, h = blockIdx.y, b = blockIdx.z;
  const int bh = b * Hh + h;
  __shared__ u16 Ql[64][72], Kl[64][72], VT[64][72], Pl[64][72];
  __shared__ float den[64];
  const int t = threadIdx.x, lane = t & 63, w = t >> 6;

  {
    const int i = t >> 2, c0 = (t & 3) * 16;
    const size_t g = ((size_t)(b * Ss + c * CC + i)) * 1024 + h * 64 + c0;
    const uint4* qp = (const uint4*)(Qb + g);
    uint4* qd = (uint4*)&Ql[i][c0]; qd[0] = qp[0]; qd[1] = qp[1];
    const uint4* kp = (const uint4*)(Kb + g);
    uint4* kd = (uint4*)&Kl[i][c0]; kd[0] = kp[0]; kd[1] = kp[1];
    const u16* vp = Vb + g;
#pragma unroll
    for (int j = 0; j < 16; ++j) VT[c0 + j][i] = vp[j];  // transpose V -> [e][i]
  }
  __syncthreads();

  // Phase A: S = Q K^T for rows w*16..+15, all 64 cols
  f32x4 sacc[4];
#pragma unroll
  for (int fj = 0; fj < 4; ++fj) sacc[fj] = f32x4{0.f, 0.f, 0.f, 0.f};
#pragma unroll
  for (int kd = 0; kd < 2; ++kd) {
    const bf16x8 aq = *(const bf16x8*)&Ql[w * 16 + (lane & 15)][kd * 32 + (lane >> 4) * 8];
#pragma unroll
    for (int fj = 0; fj < 4; ++fj) {
      const bf16x8 bk = *(const bf16x8*)&Kl[fj * 16 + (lane & 15)][kd * 32 + (lane >> 4) * 8];
      sacc[fj] = mfma16(aq, bk, sacc[fj]);
    }
  }
  float rowsum[4] = {0.f, 0.f, 0.f, 0.f};
#pragma unroll
  for (int fj = 0; fj < 4; ++fj) {
#pragma unroll
    for (int rr = 0; rr < 4; ++rr) {
      const int i_loc = w * 16 + (lane >> 4) * 4 + rr;
      const int j_loc = fj * 16 + (lane & 15);
      const float v = (j_loc <= i_loc) ? sacc[fj][rr] : 0.f;
      Pl[i_loc][j_loc] = f2bf(v);
      rowsum[rr] += v;
    }
  }
#pragma unroll
  for (int off = 1; off < 16; off <<= 1) {
#pragma unroll
    for (int rr = 0; rr < 4; ++rr) rowsum[rr] += __shfl_xor(rowsum[rr], off, 64);
  }
  if ((lane & 15) == 0) {
#pragma unroll
    for (int rr = 0; rr < 4; ++rr) den[w * 16 + (lane >> 4) * 4 + rr] = rowsum[rr];
  }
  __syncthreads();
  {
    // den[i] += Q[i]·Kspre + eps ; 4 threads per row, shfl-reduced
    const int i = t >> 2, part = t & 3;
    const float* ksp = Kspre + ((size_t)(bh * NCC + c)) * 64 + part * 16;
    float s = 0.f;
#pragma unroll
    for (int sg = 0; sg < 2; ++sg) {
      const bf16x8 q = *(const bf16x8*)&Ql[i][part * 16 + sg * 8];
#pragma unroll
      for (int j = 0; j < 8; ++j) s += bf2f((u16)q[j]) * ksp[sg * 8 + j];
    }
    s += __shfl_xor(s, 1, 64);
    s += __shfl_xor(s, 2, 64);
    if (part == 0) den[i] = den[i] + s + 1e-6f;
  }
  __syncthreads();

  // Phase B: O = Q @ KVpre + P @ V
  f32x4 oacc[4];
#pragma unroll
  for (int fj = 0; fj < 4; ++fj) oacc[fj] = f32x4{0.f, 0.f, 0.f, 0.f};
  const u16* kvb = KVpreT + ((size_t)(bh * NCC + c)) * 4096;
#pragma unroll
  for (int ks2 = 0; ks2 < 2; ++ks2) {
    const bf16x8 aq = *(const bf16x8*)&Ql[w * 16 + (lane & 15)][ks2 * 32 + (lane >> 4) * 8];
#pragma unroll
    for (int fj = 0; fj < 4; ++fj) {
      const bf16x8 bv =
          *(const bf16x8*)(kvb + (size_t)(fj * 16 + (lane & 15)) * 64 + ks2 * 32 + (lane >> 4) * 8);
      oacc[fj] = mfma16(aq, bv, oacc[fj]);
    }
  }
#pragma unroll
  for (int ks3 = 0; ks3 < 2; ++ks3) {
    const bf16x8 ap = *(const bf16x8*)&Pl[w * 16 + (lane & 15)][ks3 * 32 + (lane >> 4) * 8];
#pragma unroll
    for (int fj = 0; fj < 4; ++fj) {
      const bf16x8 bv = *(const bf16x8*)&VT[fj * 16 + (lane & 15)][ks3 * 32 + (lane >> 4) * 8];
      oacc[fj] = mfma16(ap, bv, oacc[fj]);
    }
  }
#pragma unroll
  for (int fj = 0; fj < 4; ++fj) {
#pragma unroll
    for (int rr = 0; rr < 4; ++rr) {
      const int i_loc = w * 16 + (lane >> 4) * 4 + rr;
      const int e = fj * 16 + (lane & 15);
      const float v = oacc[fj][rr] / den[i_loc];
      attn[((size_t)(b * Ss + c * CC + i_loc)) * 1024 + h * 64 + e] = f2bf(v);
    }
  }
}

// ---------------------------------------------------------------------------
extern "C" void kernel_launch(void* const* d_in, const int* in_sizes, int n_in,
                              void* d_out, int out_size, void* d_ws, size_t ws_size,
                              hipStream_t stream) {
  (void)in_sizes; (void)n_in; (void)out_size; (void)ws_size;
  const float* x  = (const float*)d_in[0];
  const float* Wq = (const float*)d_in[1];
  const float* bq = (const float*)d_in[2];
  const float* Wk = (const float*)d_in[3];
  const float* bk = (const float*)d_in[4];
  const float* Wv = (const float*)d_in[5];
  const float* bv = (const float*)d_in[6];
  const float* Wo = (const float*)d_in[7];
  const float* bo = (const float*)d_in[8];
  float* out = (float*)d_out;
  char* ws = (char*)d_ws;

  size_t off = 0;
  auto take = [&](size_t bytes) { size_t r = off; off += (bytes + 255) & ~(size_t)255; return r; };
  const size_t WQKV_B = (size_t)3072 * 1024 * 2;        // 6 MB
  const size_t WT_B   = (size_t)1024 * 1024 * 2;        // 2 MB
  const size_t BIG_B  = (size_t)16384 * 1024 * 2;       // 32 MB
  const size_t KVT_B  = (size_t)64 * NCC * 4096 * 2;    // 32 MB bf16
  const size_t KS_B   = (size_t)64 * NCC * 64 * 4;      // 1 MB f32

  u16* WqkvT  = (u16*)(ws + take(WQKV_B));
  u16* WoT    = (u16*)(ws + take(WT_B));
  size_t shared_off = take(BIG_B);                      // xbf -> KVTc -> attn alias chain
  u16* xbf    = (u16*)(ws + shared_off);
  u16* KVTc   = (u16*)(ws + shared_off);
  u16* attn   = (u16*)(ws + shared_off);
  u16* Qb     = (u16*)(ws + take(BIG_B));               // Q|K|V contiguous (3 x 32 MB)
  u16* Kb     = (u16*)(ws + take(BIG_B));
  u16* Vb     = (u16*)(ws + take(BIG_B));
  u16* KVpreT = (u16*)(ws + take(KVT_B));
  float* Ksc  = (float*)(ws + take(KS_B));
  float* Kspre= (float*)(ws + take(KS_B));

  const dim3 blk(256);
  cvt_bf16_k<<<dim3(8192), blk, 0, stream>>>(x, xbf, 16384 * 1024 / 8);
  const dim3 gT(32, 32);
  transpose_cvt_k<<<gT, blk, 0, stream>>>(Wq, WqkvT);
  transpose_cvt_k<<<gT, blk, 0, stream>>>(Wk, WqkvT + (size_t)1024 * 1024);
  transpose_cvt_k<<<gT, blk, 0, stream>>>(Wv, WqkvT + (size_t)2048 * 1024);
  transpose_cvt_k<<<gT, blk, 0, stream>>>(Wo, WoT);

  // fused QKV: N=3072 -> Qb/Kb/Vb (contiguous segments); grid (N/256, M/256)
  gemm256_k<true, false><<<dim3(12, 64), dim3(512), 0, stream>>>(
      xbf, WqkvT, bq, bk, bv, Qb, 16384, 1024);

  const dim3 gC(NCC, Hh, 4);
  chunk_kv_k<<<gC, blk, 0, stream>>>(Kb, Vb, KVTc, Ksc);   // KVTc reuses xbf slot
  prefix_k<<<dim3(64, 4), blk, 0, stream>>>(KVTc, Ksc, KVpreT, Kspre);
  chunk_out_k<<<gC, blk, 0, stream>>>(Qb, Kb, Vb, KVpreT, Kspre, attn);

  gemm256_k<false, true><<<dim3(4, 64), dim3(512), 0, stream>>>(
      attn, WoT, bo, NULL, NULL, out, 16384, 1024);
}

// Round 5
// 266.262 us; speedup vs baseline: 1.8464x; 1.0042x over previous
//
#include <hip/hip_runtime.h>
#include <stdint.h>

// ---------------------------------------------------------------------------
// LinearAttention (B=4, S=4096, HID=1024, H=16, D=64), chunked formulation.
// Round 5: 256x256 GEMM with m201-style phases: reads-before-barrier,
// double-barrier per phase (8 barriers/K-tile), counted vmcnt(4) checkpoints
// at phases 1/3, T2 swizzle, T5 setprio.  Transposes merged into one launch.
// ---------------------------------------------------------------------------

#define DEVI __device__ __forceinline__

typedef __attribute__((ext_vector_type(8))) short bf16x8;
typedef __attribute__((ext_vector_type(4))) float f32x4;
typedef unsigned short u16;

DEVI u16 f2bf(float f) {
  union { float f; uint32_t u; } x; x.f = f;
  return (u16)((x.u + 0x7FFFu + ((x.u >> 16) & 1u)) >> 16);  // RNE
}
DEVI float bf2f(u16 u) {
  union { uint32_t u; float f; } x; x.u = ((uint32_t)u) << 16;
  return x.f;
}
DEVI f32x4 mfma16(bf16x8 a, bf16x8 b, f32x4 c) {
  return __builtin_amdgcn_mfma_f32_16x16x32_bf16(a, b, c, 0, 0, 0);
}

typedef __attribute__((address_space(3))) void* lds_vp;
typedef const __attribute__((address_space(1))) void* glb_vp;
DEVI void gload_lds16(const void* g, void* l) {
  __builtin_amdgcn_global_load_lds((glb_vp)g, (lds_vp)l, 16, 0, 0);
}

#define BAR()   asm volatile("s_barrier" ::: "memory")
#define LGKM0() do { asm volatile("s_waitcnt lgkmcnt(0)" ::: "memory"); \
                     __builtin_amdgcn_sched_barrier(0); } while (0)

static constexpr int Ss  = 4096;
static constexpr int Hh  = 16;
static constexpr int CC  = 64;          // chunk length
static constexpr int NCC = Ss / CC;     // 64 chunks

// ---------------------------------------------------------------------------
// x (fp32) -> bf16, 8 elems/thread
// ---------------------------------------------------------------------------
__global__ __launch_bounds__(256) void cvt_bf16_k(const float* __restrict__ in,
                                                  u16* __restrict__ out, int n8) {
  const int i = blockIdx.x * 256 + threadIdx.x;
  if (i >= n8) return;
  const float4* p = (const float4*)(in + (size_t)i * 8);
  const float4 a = p[0], b = p[1];
  union { uint4 v; u16 s[8]; } u;
  u.s[0] = f2bf(a.x); u.s[1] = f2bf(a.y); u.s[2] = f2bf(a.z); u.s[3] = f2bf(a.w);
  u.s[4] = f2bf(b.x); u.s[5] = f2bf(b.y); u.s[6] = f2bf(b.z); u.s[7] = f2bf(b.w);
  ((uint4*)out)[i] = u.v;
}

// ---------------------------------------------------------------------------
// 4 weight transposes + fp32->bf16 in one launch: out[n][k] = bf16(in[k][n])
// z=0..2 -> WqkvT segments (Wq,Wk,Wv), z=3 -> WoT.
// ---------------------------------------------------------------------------
__global__ __launch_bounds__(256) void transpose_cvt4_k(const float* __restrict__ w0,
                                                        const float* __restrict__ w1,
                                                        const float* __restrict__ w2,
                                                        const float* __restrict__ w3,
                                                        u16* __restrict__ dqkv,
                                                        u16* __restrict__ dwo) {
  __shared__ float tl[32][33];
  const int z = blockIdx.z;
  const float* in = (z == 0) ? w0 : (z == 1) ? w1 : (z == 2) ? w2 : w3;
  u16* out = (z < 3) ? (dqkv + (size_t)z * 1024 * 1024) : dwo;
  const int tx = threadIdx.x & 31, ty = threadIdx.x >> 5;
  const int bx = blockIdx.x, by = blockIdx.y;
#pragma unroll
  for (int j = 0; j < 4; ++j)
    tl[ty + j * 8][tx] = in[(size_t)(by * 32 + ty + j * 8) * 1024 + bx * 32 + tx];
  __syncthreads();
#pragma unroll
  for (int j = 0; j < 4; ++j)
    out[(size_t)(bx * 32 + ty + j * 8) * 1024 + by * 32 + tx] = f2bf(tl[tx][ty + j * 8]);
}

// ---------------------------------------------------------------------------
// 256x256 GEMM, m201-style phases.  A bf16 [M][K], BT bf16 [N][K].
// 512 threads = 8 waves (2M x 4N), acc[8][4].  BK=64 = 2 k-halves.
// LDS slot(d, kh) = 256 rows x 32 k = 16 KB; 2 dbuf x 2 kh x {A,B} = 128 KiB.
// Per K-tile: 4 phases (kh x fj-pair), each {ds_reads; stage 2 gloads; bar;
// lgkm0; setprio+16 MFMA; [vmcnt ckpt at ph1/ph3]; bar}.  vmcnt(4) proves
// "all but the 4 newest stages landed" = the k-half needed next is in LDS.
// ---------------------------------------------------------------------------
template <bool FUSED, bool OUTF32>
__global__ __launch_bounds__(512, 2) void gemm256_k(const u16* __restrict__ A,
                                                    const u16* __restrict__ BT,
                                                    const float* __restrict__ b0,
                                                    const float* __restrict__ b1,
                                                    const float* __restrict__ b2,
                                                    void* __restrict__ out,
                                                    int M, int K) {
  __shared__ __attribute__((aligned(16))) u16 lds[65536];  // 128 KiB
  const int t = threadIdx.x, lane = t & 63, w = t >> 6;
  const int wm = w >> 2, wn = w & 3;

  // XCD-aware bijective swizzle (nwg % 8 == 0 for our grids)
  const int nx = gridDim.x;
  const int nwg = nx * gridDim.y;
  const int bid = blockIdx.y * nx + blockIdx.x;
  const int swz = (bid & 7) * (nwg >> 3) + (bid >> 3);
  const int bx = swz % nx, by = swz / nx;
  const int m0 = by * 256, n0 = bx * 256;

  const u16* gA = A + (size_t)m0 * K;
  const u16* gB = BT + (size_t)n0 * K;

  // staging: slot covers 256 rows x 32 k; thread loads rows t>>2 and +128,
  // 16B chunk (t&3); global k-chunk pre-XOR-swizzled (rule #21).
  const int sr = t >> 2;
  const int sc = (t & 3) ^ ((sr >> 1) & 3);
  auto stage = [&](const u16* gm, u16* dst, int kof) {
    gload_lds16(gm + (size_t)sr * K + kof + sc * 8, dst + t * 8);
    gload_lds16(gm + (size_t)(sr + 128) * K + kof + sc * 8, dst + 4096 + t * 8);
  };

  f32x4 acc[8][4];
#pragma unroll
  for (int i = 0; i < 8; ++i)
#pragma unroll
    for (int j = 0; j < 4; ++j) acc[i][j] = f32x4{0.f, 0.f, 0.f, 0.f};

  // prologue: tile 0, slots (A,kh0) (B,kh0) (A,kh1) (B,kh1)
  stage(gA, lds, 0);          stage(gB, lds + 32768, 0);
  stage(gA, lds + 8192, 32);  stage(gB, lds + 40960, 32);
  asm volatile("s_waitcnt vmcnt(4)" ::: "memory");  // kh0 landed, kh1 in flight
  BAR();

  const int fr = lane & 15, kq = lane >> 4;
  const int rdko = ((kq ^ ((fr >> 1) & 3)) << 3);  // swizzled k-chunk (u16 units)
  const int arow0 = wm * 128 + fr;
  const int brow0 = wn * 64 + fr;

  const int nk = K >> 6;
  for (int kt = 0; kt < nk; ++kt) {
    const int d = kt & 1;
    const bool pf = (kt + 1 < nk);
    const int kon = (kt + 1) << 6;
    u16* Ac = lds + d * 16384;
    u16* Bc = lds + 32768 + d * 16384;
    u16* An = lds + (d ^ 1) * 16384;
    u16* Bn = lds + 32768 + (d ^ 1) * 16384;
    bf16x8 af[8], bg0, bg1;
#pragma unroll
    for (int h = 0; h < 2; ++h) {
      const u16* Ah = Ac + h * 8192;
      const u16* Bh = Bc + h * 8192;
      // ---- phase 2h: A frags + B fj{0,1}  (10 ds_read_b128) ----
#pragma unroll
      for (int fi = 0; fi < 8; ++fi)
        af[fi] = *(const bf16x8*)(Ah + (arow0 + fi * 16) * 32 + rdko);
      bg0 = *(const bf16x8*)(Bh + brow0 * 32 + rdko);
      bg1 = *(const bf16x8*)(Bh + (brow0 + 16) * 32 + rdko);
      if (pf) stage(gA, An + h * 8192, kon + h * 32);
      BAR();
      LGKM0();
      __builtin_amdgcn_s_setprio(1);
#pragma unroll
      for (int fi = 0; fi < 8; ++fi) {
        acc[fi][0] = mfma16(af[fi], bg0, acc[fi][0]);
        acc[fi][1] = mfma16(af[fi], bg1, acc[fi][1]);
      }
      __builtin_amdgcn_s_setprio(0);
      __builtin_amdgcn_sched_barrier(0);
      BAR();
      // ---- phase 2h+1: B fj{2,3}  (2 ds_read_b128) ----
      bg0 = *(const bf16x8*)(Bh + (brow0 + 32) * 32 + rdko);
      bg1 = *(const bf16x8*)(Bh + (brow0 + 48) * 32 + rdko);
      if (pf) stage(gB, Bn + h * 8192, kon + h * 32);
      BAR();
      LGKM0();
      __builtin_amdgcn_s_setprio(1);
#pragma unroll
      for (int fi = 0; fi < 8; ++fi) {
        acc[fi][2] = mfma16(af[fi], bg0, acc[fi][2]);
        acc[fi][3] = mfma16(af[fi], bg1, acc[fi][3]);
      }
      __builtin_amdgcn_s_setprio(0);
      __builtin_amdgcn_sched_barrier(0);
      // checkpoint: ph1 gates this tile's kh1; ph3 gates next tile's kh0
      if (h == 0) {
        if (pf) asm volatile("s_waitcnt vmcnt(4)" ::: "memory");
        else    asm volatile("s_waitcnt vmcnt(0)" ::: "memory");
      } else if (pf) {
        asm volatile("s_waitcnt vmcnt(4)" ::: "memory");
      }
      BAR();
    }
  }

  // ---------------- epilogue: LDS-staged coalesced stores ----------------
  const int rowg = (lane >> 4) * 4;
  if constexpr (!OUTF32) {
    __syncthreads();
    const int seg  = FUSED ? (n0 >> 10) : 0;
    const int lcol0 = FUSED ? (n0 & 1023) : n0;
    const float* bp = b0;
    if constexpr (FUSED) bp = (seg == 0) ? b0 : (seg == 1) ? b1 : b2;
#pragma unroll
    for (int fj = 0; fj < 4; ++fj) {
      const int col = wn * 64 + fj * 16 + fr;
      const float bv = bp[lcol0 + col];
#pragma unroll
      for (int fi = 0; fi < 8; ++fi) {
#pragma unroll
        for (int rr = 0; rr < 4; ++rr) {
          const int row = wm * 128 + fi * 16 + rowg + rr;
          float v = acc[fi][fj][rr] + bv;
          if (FUSED && seg < 2) v = (v > 0.f) ? (v + 1.f) : __expf(v);
          lds[row * 256 + (((col >> 3) ^ ((row >> 2) & 31)) << 3) + (col & 7)] = f2bf(v);
        }
      }
    }
    __syncthreads();
    u16* outp = (u16*)out + (size_t)seg * M * 1024 + (size_t)m0 * 1024 + lcol0;
#pragma unroll
    for (int it = 0; it < 16; ++it) {
      const int g = it * 512 + t;
      const int row = g >> 5, c16 = g & 31;
      const uint4 v = *(const uint4*)&lds[row * 256 + ((c16 ^ ((row >> 2) & 31)) << 3)];
      *(uint4*)(outp + (size_t)row * 1024 + c16 * 8) = v;
    }
  } else {
    float* flds = (float*)lds;
#pragma unroll
    for (int pass = 0; pass < 2; ++pass) {
      __syncthreads();
      if (wm == pass) {
#pragma unroll
        for (int fj = 0; fj < 4; ++fj) {
          const int col = wn * 64 + fj * 16 + fr;
          const float bv = b0[n0 + col];
#pragma unroll
          for (int fi = 0; fi < 8; ++fi) {
#pragma unroll
            for (int rr = 0; rr < 4; ++rr) {
              const int rl = fi * 16 + rowg + rr;
              flds[rl * 256 + (((col >> 2) ^ ((rl >> 2) & 63)) << 2) + (col & 3)] =
                  acc[fi][fj][rr] + bv;
            }
          }
        }
      }
      __syncthreads();
      float* outp = (float*)out + (size_t)(m0 + pass * 128) * 1024 + n0;
#pragma unroll
      for (int it = 0; it < 16; ++it) {
        const int g = it * 512 + t;
        const int row = g >> 6, c16 = g & 63;
        const uint4 v = *(const uint4*)&flds[row * 256 + ((c16 ^ ((row >> 2) & 63)) << 2)];
        *(uint4*)(outp + (size_t)row * 1024 + c16 * 4) = v;
      }
    }
  }
}

// ---------------------------------------------------------------------------
// per-chunk KVT_c[e][d] = sum_i V[i][e]*K[i][d]  (bf16 out, via MFMA),
// Ks_c[d] = sum_i K[i][d] (f32).  grid (NCC, H, B), 256 threads (4 waves).
// ---------------------------------------------------------------------------
__global__ __launch_bounds__(256) void chunk_kv_k(const u16* __restrict__ Kb,
                                                  const u16* __restrict__ Vb,
                                                  u16* __restrict__ KVTc,
                                                  float* __restrict__ Ksc) {
  const int c = blockIdx.x, h = blockIdx.y, b = blockIdx.z;
  __shared__ u16 KT[64][72], VT[64][72];   // transposed: [d][i] / [e][i]
  const int t = threadIdx.x, lane = t & 63, w = t >> 6;
  {
    const int i = t >> 2, c0 = (t & 3) * 16;
    const size_t g = ((size_t)(b * Ss + c * CC + i)) * 1024 + h * 64 + c0;
    const u16* kp = Kb + g;
    const u16* vp = Vb + g;
#pragma unroll
    for (int j = 0; j < 16; ++j) { KT[c0 + j][i] = kp[j]; VT[c0 + j][i] = vp[j]; }
  }
  __syncthreads();
  f32x4 acc[4];
#pragma unroll
  for (int j = 0; j < 4; ++j) acc[j] = f32x4{0.f, 0.f, 0.f, 0.f};
  const int fr = lane & 15, kq = (lane >> 4) * 8;
#pragma unroll
  for (int kk = 0; kk < 2; ++kk) {
    const bf16x8 av = *(const bf16x8*)&VT[w * 16 + fr][kk * 32 + kq];
#pragma unroll
    for (int fj = 0; fj < 4; ++fj) {
      const bf16x8 bk = *(const bf16x8*)&KT[fj * 16 + fr][kk * 32 + kq];
      acc[fj] = mfma16(av, bk, acc[fj]);
    }
  }
  const size_t base = ((size_t)((b * Hh + h) * NCC + c)) * 4096;
#pragma unroll
  for (int fj = 0; fj < 4; ++fj)
#pragma unroll
    for (int rr = 0; rr < 4; ++rr) {
      const int e = w * 16 + (lane >> 4) * 4 + rr;
      const int d = fj * 16 + fr;
      KVTc[base + (size_t)e * 64 + d] = f2bf(acc[fj][rr]);
    }
  if (t < 64) {
    float s = 0.f;
#pragma unroll
    for (int ii = 0; ii < 8; ++ii) {
      const bf16x8 kv = *(const bf16x8*)&KT[t][ii * 8];
#pragma unroll
      for (int j = 0; j < 8; ++j) s += bf2f((u16)kv[j]);
    }
    Ksc[((size_t)((b * Hh + h) * NCC + c)) * 64 + t] = s;
  }
}

// ---------------------------------------------------------------------------
// exclusive prefix over chunks per (b,h).  grid (64, 4); thread owns 4
// consecutive elements (uint2 loads/stores).
// ---------------------------------------------------------------------------
__global__ __launch_bounds__(256) void prefix_k(const u16* __restrict__ KVTc,
                                                const float* __restrict__ Ksc,
                                                u16* __restrict__ KVpreT,
                                                float* __restrict__ Kspre) {
  const int bh = blockIdx.x, eg = blockIdx.y;
  const int t = threadIdx.x;
  const int e4 = eg * 1024 + t * 4;
  const u16* src = KVTc + (size_t)bh * NCC * 4096 + e4;
  u16* dst = KVpreT + (size_t)bh * NCC * 4096 + e4;
  const float* kss = Ksc + (size_t)bh * NCC * 64 + t;
  float* ksd = Kspre + (size_t)bh * NCC * 64 + t;
  float run[4] = {0.f, 0.f, 0.f, 0.f};
  float rk = 0.f;
  for (int c = 0; c < NCC; ++c) {
    union { uint2 v; u16 s[4]; } in, ov;
    in.v = *(const uint2*)(src + (size_t)c * 4096);
#pragma unroll
    for (int j = 0; j < 4; ++j) { ov.s[j] = f2bf(run[j]); run[j] += bf2f(in.s[j]); }
    *(uint2*)(dst + (size_t)c * 4096) = ov.v;
    if (eg == 0 && t < 64) { ksd[(size_t)c * 64] = rk; rk += kss[(size_t)c * 64]; }
  }
}

// ---------------------------------------------------------------------------
// per-(b,h,c) chunk output.  grid (NCC, H, B), 256 threads (4 waves).
// ---------------------------------------------------------------------------
__global__ __launch_bounds__(256) void chunk_out_k(const u16* __restrict__ Qb,
                                                   const u16* __restrict__ Kb,
                                                   const u16* __restrict__ Vb,
                                                   const u16* __restrict__ KVpreT,
                                                   const float* __restrict__ Kspre,
                                                   u16* __restrict__ attn) {
  const int c = blockIdx.x, h = blockIdx.y, b = blockIdx.z;
  const int bh = b * Hh + h;
  __shared__ u16 Ql[64][72], Kl[64][72], VT[64][72], Pl[64][72];
  __shared__ float den[64];
  const int t = threadIdx.x, lane = t & 63, w = t >> 6;

  {
    const int i = t >> 2, c0 = (t & 3) * 16;
    const size_t g = ((size_t)(b * Ss + c * CC + i)) * 1024 + h * 64 + c0;
    const uint4* qp = (const uint4*)(Qb + g);
    uint4* qd = (uint4*)&Ql[i][c0]; qd[0] = qp[0]; qd[1] = qp[1];
    const uint4* kp = (const uint4*)(Kb + g);
    uint4* kd = (uint4*)&Kl[i][c0]; kd[0] = kp[0]; kd[1] = kp[1];
    const u16* vp = Vb + g;
#pragma unroll
    for (int j = 0; j < 16; ++j) VT[c0 + j][i] = vp[j];  // transpose V -> [e][i]
  }
  __syncthreads();

  // Phase A: S = Q K^T for rows w*16..+15, all 64 cols
  f32x4 sacc[4];
#pragma unroll
  for (int fj = 0; fj < 4; ++fj) sacc[fj] = f32x4{0.f, 0.f, 0.f, 0.f};
#pragma unroll
  for (int kd = 0; kd < 2; ++kd) {
    const bf16x8 aq = *(const bf16x8*)&Ql[w * 16 + (lane & 15)][kd * 32 + (lane >> 4) * 8];
#pragma unroll
    for (int fj = 0; fj < 4; ++fj) {
      const bf16x8 bk = *(const bf16x8*)&Kl[fj * 16 + (lane & 15)][kd * 32 + (lane >> 4) * 8];
      sacc[fj] = mfma16(aq, bk, sacc[fj]);
    }
  }
  float rowsum[4] = {0.f, 0.f, 0.f, 0.f};
#pragma unroll
  for (int fj = 0; fj < 4; ++fj) {
#pragma unroll
    for (int rr = 0; rr < 4; ++rr) {
      const int i_loc = w * 16 + (lane >> 4) * 4 + rr;
      const int j_loc = fj * 16 + (lane & 15);
      const float v = (j_loc <= i_loc) ? sacc[fj][rr] : 0.f;
      Pl[i_loc][j_loc] = f2bf(v);
      rowsum[rr] += v;
    }
  }
#pragma unroll
  for (int off = 1; off < 16; off <<= 1) {
#pragma unroll
    for (int rr = 0; rr < 4; ++rr) rowsum[rr] += __shfl_xor(rowsum[rr], off, 64);
  }
  if ((lane & 15) == 0) {
#pragma unroll
    for (int rr = 0; rr < 4; ++rr) den[w * 16 + (lane >> 4) * 4 + rr] = rowsum[rr];
  }
  __syncthreads();
  {
    // den[i] += Q[i]·Kspre + eps ; 4 threads per row, shfl-reduced
    const int i = t >> 2, part = t & 3;
    const float* ksp = Kspre + ((size_t)(bh * NCC + c)) * 64 + part * 16;
    float s = 0.f;
#pragma unroll
    for (int sg = 0; sg < 2; ++sg) {
      const bf16x8 q = *(const bf16x8*)&Ql[i][part * 16 + sg * 8];
#pragma unroll
      for (int j = 0; j < 8; ++j) s += bf2f((u16)q[j]) * ksp[sg * 8 + j];
    }
    s += __shfl_xor(s, 1, 64);
    s += __shfl_xor(s, 2, 64);
    if (part == 0) den[i] = den[i] + s + 1e-6f;
  }
  __syncthreads();

  // Phase B: O = Q @ KVpre + P @ V
  f32x4 oacc[4];
#pragma unroll
  for (int fj = 0; fj < 4; ++fj) oacc[fj] = f32x4{0.f, 0.f, 0.f, 0.f};
  const u16* kvb = KVpreT + ((size_t)(bh * NCC + c)) * 4096;
#pragma unroll
  for (int ks2 = 0; ks2 < 2; ++ks2) {
    const bf16x8 aq = *(const bf16x8*)&Ql[w * 16 + (lane & 15)][ks2 * 32 + (lane >> 4) * 8];
#pragma unroll
    for (int fj = 0; fj < 4; ++fj) {
      const bf16x8 bv =
          *(const bf16x8*)(kvb + (size_t)(fj * 16 + (lane & 15)) * 64 + ks2 * 32 + (lane >> 4) * 8);
      oacc[fj] = mfma16(aq, bv, oacc[fj]);
    }
  }
#pragma unroll
  for (int ks3 = 0; ks3 < 2; ++ks3) {
    const bf16x8 ap = *(const bf16x8*)&Pl[w * 16 + (lane & 15)][ks3 * 32 + (lane >> 4) * 8];
#pragma unroll
    for (int fj = 0; fj < 4; ++fj) {
      const bf16x8 bv = *(const bf16x8*)&VT[fj * 16 + (lane & 15)][ks3 * 32 + (lane >> 4) * 8];
      oacc[fj] = mfma16(ap, bv, oacc[fj]);
    }
  }
#pragma unroll
  for (int fj = 0; fj < 4; ++fj) {
#pragma unroll
    for (int rr = 0; rr < 4; ++rr) {
      const int i_loc = w * 16 + (lane >> 4) * 4 + rr;
      const int e = fj * 16 + (lane & 15);
      const float v = oacc[fj][rr] / den[i_loc];
      attn[((size_t)(b * Ss + c * CC + i_loc)) * 1024 + h * 64 + e] = f2bf(v);
    }
  }
}

// ---------------------------------------------------------------------------
extern "C" void kernel_launch(void* const* d_in, const int* in_sizes, int n_in,
                              void* d_out, int out_size, void* d_ws, size_t ws_size,
                              hipStream_t stream) {
  (void)in_sizes; (void)n_in; (void)out_size; (void)ws_size;
  const float* x  = (const float*)d_in[0];
  const float* Wq = (const float*)d_in[1];
  const float* bq = (const float*)d_in[2];
  const float* Wk = (const float*)d_in[3];
  const float* bk = (const float*)d_in[4];
  const float* Wv = (const float*)d_in[5];
  const float* bv = (const float*)d_in[6];
  const float* Wo = (const float*)d_in[7];
  const float* bo = (const float*)d_in[8];
  float* out = (float*)d_out;
  char* ws = (char*)d_ws;

  size_t off = 0;
  auto take = [&](size_t bytes) { size_t r = off; off += (bytes + 255) & ~(size_t)255; return r; };
  const size_t WQKV_B = (size_t)3072 * 1024 * 2;        // 6 MB
  const size_t WT_B   = (size_t)1024 * 1024 * 2;        // 2 MB
  const size_t BIG_B  = (size_t)16384 * 1024 * 2;       // 32 MB
  const size_t KVT_B  = (size_t)64 * NCC * 4096 * 2;    // 32 MB bf16
  const size_t KS_B   = (size_t)64 * NCC * 64 * 4;      // 1 MB f32

  u16* WqkvT  = (u16*)(ws + take(WQKV_B));
  u16* WoT    = (u16*)(ws + take(WT_B));
  size_t shared_off = take(BIG_B);                      // xbf -> KVTc -> attn alias chain
  u16* xbf    = (u16*)(ws + shared_off);
  u16* KVTc   = (u16*)(ws + shared_off);
  u16* attn   = (u16*)(ws + shared_off);
  u16* Qb     = (u16*)(ws + take(BIG_B));               // Q|K|V contiguous (3 x 32 MB)
  u16* Kb     = (u16*)(ws + take(BIG_B));
  u16* Vb     = (u16*)(ws + take(BIG_B));
  u16* KVpreT = (u16*)(ws + take(KVT_B));
  float* Ksc  = (float*)(ws + take(KS_B));
  float* Kspre= (float*)(ws + take(KS_B));

  const dim3 blk(256);
  cvt_bf16_k<<<dim3(8192), blk, 0, stream>>>(x, xbf, 16384 * 1024 / 8);
  transpose_cvt4_k<<<dim3(32, 32, 4), blk, 0, stream>>>(Wq, Wk, Wv, Wo, WqkvT, WoT);

  // fused QKV: N=3072 -> Qb/Kb/Vb (contiguous segments); grid (N/256, M/256)
  gemm256_k<true, false><<<dim3(12, 64), dim3(512), 0, stream>>>(
      xbf, WqkvT, bq, bk, bv, Qb, 16384, 1024);

  const dim3 gC(NCC, Hh, 4);
  chunk_kv_k<<<gC, blk, 0, stream>>>(Kb, Vb, KVTc, Ksc);   // KVTc reuses xbf slot
  prefix_k<<<dim3(64, 4), blk, 0, stream>>>(KVTc, Ksc, KVpreT, Kspre);
  chunk_out_k<<<gC, blk, 0, stream>>>(Qb, Kb, Vb, KVpreT, Kspre, attn);

  gemm256_k<false, true><<<dim3(4, 64), dim3(512), 0, stream>>>(
      attn, WoT, bo, NULL, NULL, out, 16384, 1024);
}